// Round 1
// baseline (358.666 us; speedup 1.0000x reference)
//
#include <hip/hip_runtime.h>
#include <hip/hip_bf16.h>
#include <math.h>

#define B_   16
#define L_   1024
#define F_   64
#define D_   256
#define S_   2
#define N_   16
#define H_   32
#define EPS_ 1e-5f
#define BL_  (B_*L_)

// ---------------------------------------------------------------------------
// Kernel 1: h = x @ W_in + b_in   (M=BL=16384, K=64, N=256)
// 64x64 tile per block, 256 threads, each thread 4x4 micro-tile. Full K staged.
// ---------------------------------------------------------------------------
__global__ __launch_bounds__(256) void k_inproj(const float* __restrict__ x,
                                                const float* __restrict__ Win,
                                                const float* __restrict__ bin,
                                                float* __restrict__ h)
{
    const int m0 = blockIdx.x * 64;
    const int n0 = blockIdx.y * 64;
    const int tx = threadIdx.x, ty = threadIdx.y;   // 16 x 16
    const int tid = ty * 16 + tx;

    __shared__ float As[64][68];   // [k][m], pad 68 (272B, 16B-aligned rows)
    __shared__ float Bs[64][68];   // [k][n]

    // Load A: x[m0+r][k] (row stride F_=64), float4 along k. 1024 float4s.
    for (int i = tid; i < 64 * 16; i += 256) {
        int r  = i >> 4;
        int k4 = i & 15;
        float4 v = *(const float4*)(x + (size_t)(m0 + r) * F_ + k4 * 4);
        As[k4*4+0][r] = v.x; As[k4*4+1][r] = v.y;
        As[k4*4+2][r] = v.z; As[k4*4+3][r] = v.w;
    }
    // Load B: Win[k][n0+n]
    for (int i = tid; i < 64 * 16; i += 256) {
        int k  = i >> 4;
        int n4 = i & 15;
        *(float4*)&Bs[k][n4*4] = *(const float4*)(Win + (size_t)k * D_ + n0 + n4*4);
    }
    __syncthreads();

    float acc[4][4] = {};
    #pragma unroll 8
    for (int k = 0; k < 64; ++k) {
        float4 a = *(const float4*)&As[k][ty * 4];
        float4 b = *(const float4*)&Bs[k][tx * 4];
        float av[4] = {a.x, a.y, a.z, a.w};
        float bv[4] = {b.x, b.y, b.z, b.w};
        #pragma unroll
        for (int i = 0; i < 4; ++i)
            #pragma unroll
            for (int j = 0; j < 4; ++j)
                acc[i][j] += av[i] * bv[j];
    }

    float bv[4];
    #pragma unroll
    for (int j = 0; j < 4; ++j) bv[j] = bin[n0 + tx*4 + j];
    #pragma unroll
    for (int i = 0; i < 4; ++i) {
        int row = m0 + ty * 4 + i;
        float4 o;
        o.x = acc[i][0] + bv[0];
        o.y = acc[i][1] + bv[1];
        o.z = acc[i][2] + bv[2];
        o.w = acc[i][3] + bv[3];
        *(float4*)(h + (size_t)row * D_ + n0 + tx * 4) = o;
    }
}

// ---------------------------------------------------------------------------
// Kernel 2: delta = softplus(h@Wd + bd) * sigmoid(h@Wtau)   per state s
// Dual-accumulator GEMM: M=16384, K=256, N=256; 64x64 tile, K chunks of 16.
// ---------------------------------------------------------------------------
__global__ __launch_bounds__(256) void k_deltatau(const float* __restrict__ h,
                                                  const float* __restrict__ Wd,
                                                  const float* __restrict__ bd,
                                                  const float* __restrict__ Wt,
                                                  float* __restrict__ delta)
{
    const int s  = blockIdx.z;
    const int m0 = blockIdx.x * 64;
    const int n0 = blockIdx.y * 64;
    const int tx = threadIdx.x, ty = threadIdx.y;
    const int tid = ty * 16 + tx;

    const float* wd = Wd + (size_t)s * D_ * D_;
    const float* wt = Wt + (size_t)s * D_ * D_;

    __shared__ float As[16][68];
    __shared__ float Bd[16][68];
    __shared__ float Bt[16][68];

    float accd[4][4] = {};
    float acct[4][4] = {};

    for (int k0 = 0; k0 < D_; k0 += 16) {
        {   // A tile: h[m0+r][k0..k0+15], 256 float4s (one per thread)
            int r  = tid >> 2;
            int k4 = tid & 3;
            float4 v = *(const float4*)(h + (size_t)(m0 + r) * D_ + k0 + k4 * 4);
            As[k4*4+0][r] = v.x; As[k4*4+1][r] = v.y;
            As[k4*4+2][r] = v.z; As[k4*4+3][r] = v.w;
        }
        {   // B tiles: W[k0+k][n0..n0+63]
            int k  = tid >> 4;
            int n4 = tid & 15;
            *(float4*)&Bd[k][n4*4] = *(const float4*)(wd + (size_t)(k0 + k) * D_ + n0 + n4*4);
            *(float4*)&Bt[k][n4*4] = *(const float4*)(wt + (size_t)(k0 + k) * D_ + n0 + n4*4);
        }
        __syncthreads();

        #pragma unroll
        for (int k = 0; k < 16; ++k) {
            float4 a = *(const float4*)&As[k][ty * 4];
            float4 b = *(const float4*)&Bd[k][tx * 4];
            float4 c = *(const float4*)&Bt[k][tx * 4];
            float av[4] = {a.x, a.y, a.z, a.w};
            float bv[4] = {b.x, b.y, b.z, b.w};
            float cv[4] = {c.x, c.y, c.z, c.w};
            #pragma unroll
            for (int i = 0; i < 4; ++i)
                #pragma unroll
                for (int j = 0; j < 4; ++j) {
                    accd[i][j] += av[i] * bv[j];
                    acct[i][j] += av[i] * cv[j];
                }
        }
        __syncthreads();
    }

    float bdv[4];
    #pragma unroll
    for (int j = 0; j < 4; ++j) bdv[j] = bd[s * D_ + n0 + tx*4 + j];

    float* dout = delta + (size_t)s * BL_ * D_;
    #pragma unroll
    for (int i = 0; i < 4; ++i) {
        int row = m0 + ty * 4 + i;
        float o[4];
        #pragma unroll
        for (int j = 0; j < 4; ++j) {
            float pd = accd[i][j] + bdv[j];
            float sp = fmaxf(pd, 0.f) + log1pf(__expf(-fabsf(pd)));   // softplus
            float sg = 1.f / (1.f + __expf(-acct[i][j]));             // sigmoid
            o[j] = sp * sg;
        }
        float4 v = {o[0], o[1], o[2], o[3]};
        *(float4*)(dout + (size_t)row * D_ + n0 + tx * 4) = v;
    }
}

// ---------------------------------------------------------------------------
// Kernel 3: Bm = h @ WB   per s  (M=16384, K=256, N=16)
// block = 256 thr = 16 rows x 16 n
// ---------------------------------------------------------------------------
__global__ __launch_bounds__(256) void k_bm(const float* __restrict__ h,
                                            const float* __restrict__ WB,
                                            float* __restrict__ Bm)
{
    const int s   = blockIdx.y;
    const int tid = threadIdx.x;
    const int row = blockIdx.x * 16 + (tid >> 4);
    const int n   = tid & 15;
    const float* wb = WB + (size_t)s * D_ * N_;
    const float* hr = h + (size_t)row * D_;
    float acc = 0.f;
    #pragma unroll 4
    for (int k = 0; k < D_; k += 4) {
        float4 hv = *(const float4*)(hr + k);
        acc += hv.x * wb[(k+0)*N_ + n];
        acc += hv.y * wb[(k+1)*N_ + n];
        acc += hv.z * wb[(k+2)*N_ + n];
        acc += hv.w * wb[(k+3)*N_ + n];
    }
    Bm[((size_t)s * BL_ + row) * N_ + n] = acc;
}

// ---------------------------------------------------------------------------
// Kernel 4: recurrence over L for final state only.
// block = 256 thr = 16 d x 16 n chains for one (s, b, d-tile). LDS-staged
// chunks of 8 timesteps.
// ---------------------------------------------------------------------------
__global__ __launch_bounds__(256) void k_scan(const float* __restrict__ delta,
                                              const float* __restrict__ h,
                                              const float* __restrict__ Bm,
                                              const float* __restrict__ A_log,
                                              float* __restrict__ states)
{
    const int d0 = blockIdx.x * 16;
    const int b  = blockIdx.y;
    const int s  = blockIdx.z;
    const int tid = threadIdx.x;
    const int dl = tid & 15;
    const int nl = tid >> 4;
    const int d  = d0 + dl;

    const float A = -__expf(A_log[((size_t)s * D_ + d) * N_ + nl]);

    const float* dptr = delta + ((size_t)s * BL_ + (size_t)b * L_) * D_ + d0;
    const float* hptr = h + ((size_t)b * L_) * D_ + d0;
    const float* bptr = Bm + ((size_t)s * BL_ + (size_t)b * L_) * N_;

    __shared__ float sd[8][16];
    __shared__ float sh[8][16];
    __shared__ float sb[8][16];

    float state = 0.f;
    for (int t0 = 0; t0 < L_; t0 += 8) {
        if (tid < 96) {
            int grp = tid >> 5;     // 0: delta, 1: h, 2: Bm
            int i   = tid & 31;     // 32 float4 = 128 floats each
            int tt  = i >> 2;
            int q   = i & 3;
            if (grp == 0) {
                *(float4*)&sd[tt][q*4] = *(const float4*)(dptr + (size_t)(t0+tt)*D_ + q*4);
            } else if (grp == 1) {
                *(float4*)&sh[tt][q*4] = *(const float4*)(hptr + (size_t)(t0+tt)*D_ + q*4);
            } else {
                *(float4*)&sb[tt][q*4] = *(const float4*)(bptr + (size_t)(t0+tt)*N_ + q*4);
            }
        }
        __syncthreads();
        #pragma unroll
        for (int tt = 0; tt < 8; ++tt) {
            float dlt = sd[tt][dl];
            float bx  = dlt * sb[tt][nl] * sh[tt][dl];
            state = __expf(dlt * A) * state + bx;
        }
        __syncthreads();
    }
    states[(((size_t)s * B_ + b) * D_ + d) * N_ + nl] = state;
}

// ---------------------------------------------------------------------------
// Kernel 5: final readout. One block per batch element b.
// ---------------------------------------------------------------------------
__global__ __launch_bounds__(256) void k_final(const float* __restrict__ h,
                                               const float* __restrict__ states,
                                               const float* __restrict__ WC,
                                               const float* __restrict__ Dp,
                                               const float* __restrict__ Wout,
                                               const float* __restrict__ ln_g,
                                               const float* __restrict__ ln_b,
                                               const float* __restrict__ W1,
                                               const float* __restrict__ b1,
                                               const float* __restrict__ W2,
                                               const float* __restrict__ b2,
                                               float* __restrict__ out)
{
    const int b   = blockIdx.x;
    const int tid = threadIdx.x;

    __shared__ float hl[D_];
    __shared__ float cm[S_][N_];
    __shared__ float ys[S_][D_];
    __shared__ float lastv[D_];
    __shared__ float zv[D_];
    __shared__ float red1[256];
    __shared__ float red2[256];
    __shared__ float r1[H_];

    hl[tid] = h[((size_t)b * L_ + (L_ - 1)) * D_ + tid];
    __syncthreads();

    // Cm at last timestep: 32 outputs (s,n)
    if (tid < S_ * N_) {
        int s = tid >> 4, n = tid & 15;
        float a = 0.f;
        for (int d = 0; d < D_; ++d) a += hl[d] * WC[((size_t)s * D_ + d) * N_ + n];
        cm[s][n] = a;
    }
    __syncthreads();

    // y_last per (s,d)
    for (int s = 0; s < S_; ++s) {
        const float* st = states + (((size_t)s * B_ + b) * D_ + tid) * N_;
        float a = 0.f;
        #pragma unroll
        for (int n = 0; n < N_; ++n) a += st[n] * cm[s][n];
        ys[s][tid] = a + hl[tid] * Dp[s * D_ + tid];
    }
    __syncthreads();

    // last[e] = mean_s ( y_last[s] @ Wout[s] )[e]
    {
        float a = 0.f;
        for (int s = 0; s < S_; ++s) {
            const float* wo = Wout + (size_t)s * D_ * D_;
            for (int d = 0; d < D_; ++d) a += ys[s][d] * wo[(size_t)d * D_ + tid];
        }
        lastv[tid] = a * (1.f / S_);
    }

    // LayerNorm over D: sum and sum-of-squares reductions
    float v = lastv[tid];
    red1[tid] = v;
    red2[tid] = v * v;
    __syncthreads();
    for (int off = 128; off > 0; off >>= 1) {
        if (tid < off) { red1[tid] += red1[tid + off]; red2[tid] += red2[tid + off]; }
        __syncthreads();
    }
    const float mu  = red1[0] * (1.f / D_);
    const float var = red2[0] * (1.f / D_) - mu * mu;
    const float z = (v - mu) * rsqrtf(var + EPS_) * ln_g[tid] + ln_b[tid];
    zv[tid] = z;
    __syncthreads();

    // MLP: z @ W1 + b1 -> relu -> @ W2 + b2
    if (tid < H_) {
        float a = b1[tid];
        for (int e = 0; e < D_; ++e) a += zv[e] * W1[(size_t)e * H_ + tid];
        r1[tid] = fmaxf(a, 0.f);
    }
    __syncthreads();
    if (tid == 0) {
        float a = b2[0];
        for (int j = 0; j < H_; ++j) a += r1[j] * W2[j];
        out[b] = a;
    }
}

// ---------------------------------------------------------------------------
extern "C" void kernel_launch(void* const* d_in, const int* in_sizes, int n_in,
                              void* d_out, int out_size, void* d_ws, size_t ws_size,
                              hipStream_t stream)
{
    const float* x     = (const float*)d_in[0];
    const float* Win   = (const float*)d_in[1];
    const float* bin   = (const float*)d_in[2];
    const float* Wd    = (const float*)d_in[3];
    const float* bd    = (const float*)d_in[4];
    const float* WB    = (const float*)d_in[5];
    const float* WC    = (const float*)d_in[6];
    const float* Wtau  = (const float*)d_in[7];
    const float* A_log = (const float*)d_in[8];
    const float* Dp    = (const float*)d_in[9];
    const float* Wout  = (const float*)d_in[10];
    const float* ln_g  = (const float*)d_in[11];
    const float* ln_b  = (const float*)d_in[12];
    const float* W1    = (const float*)d_in[13];
    const float* b1    = (const float*)d_in[14];
    const float* W2    = (const float*)d_in[15];
    const float* b2    = (const float*)d_in[16];
    float* out = (float*)d_out;

    char* ws = (char*)d_ws;
    float* h      = (float*)(ws);                                  // 16 MiB
    float* delta  = (float*)(ws + (size_t)16 * 1024 * 1024);       // 32 MiB (S,BL,D)
    float* Bm     = (float*)(ws + (size_t)48 * 1024 * 1024);       //  2 MiB (S,BL,N)
    float* states = (float*)(ws + (size_t)50 * 1024 * 1024);       // 0.5 MiB (S,B,D,N)

    dim3 blk2d(16, 16);
    hipLaunchKernelGGL(k_inproj,   dim3(BL_/64, D_/64),       blk2d,     0, stream, x, Win, bin, h);
    hipLaunchKernelGGL(k_deltatau, dim3(BL_/64, D_/64, S_),   blk2d,     0, stream, h, Wd, bd, Wtau, delta);
    hipLaunchKernelGGL(k_bm,       dim3(BL_/16, S_),          dim3(256), 0, stream, h, WB, Bm);
    hipLaunchKernelGGL(k_scan,     dim3(D_/16, B_, S_),       dim3(256), 0, stream, delta, h, Bm, A_log, states);
    hipLaunchKernelGGL(k_final,    dim3(B_),                  dim3(256), 0, stream,
                       h, states, WC, Dp, Wout, ln_g, ln_b, W1, b1, W2, b2, out);
}

// Round 2
// 293.439 us; speedup vs baseline: 1.2223x; 1.2223x over previous
//
#include <hip/hip_runtime.h>
#include <hip/hip_bf16.h>
#include <math.h>

#define B_   16
#define L_   1024
#define F_   64
#define D_   256
#define S_   2
#define N_   16
#define H_   32
#define EPS_ 1e-5f
#define BL_  (B_*L_)

typedef __attribute__((ext_vector_type(8))) short  bf16x8;
typedef __attribute__((ext_vector_type(4))) float  f32x4;

typedef const __attribute__((address_space(1))) void* gas_ptr;
typedef __attribute__((address_space(3))) void*       las_ptr;

__device__ inline void async_copy16(const void* g, void* l) {
    __builtin_amdgcn_global_load_lds((gas_ptr)g, (las_ptr)l, 16, 0, 0);
}

__device__ inline unsigned short f2bf_rne(float x) {
    union { float f; unsigned u; } v; v.f = x;
    unsigned r = v.u + 0x7fff + ((v.u >> 16) & 1);
    return (unsigned short)(r >> 16);
}
__device__ inline float bf2f(unsigned short h) {
    union { float f; unsigned u; } v; v.u = ((unsigned)h) << 16;
    return v.f;
}

// ---------------------------------------------------------------------------
// Kernel 1: h = x @ W_in + b_in   (M=BL=16384, K=64, N=256)
// Also emits split-bf16 h_hi/h_lo for the MFMA deltatau GEMM.
// ---------------------------------------------------------------------------
__global__ __launch_bounds__(256) void k_inproj(const float* __restrict__ x,
                                                const float* __restrict__ Win,
                                                const float* __restrict__ bin,
                                                float* __restrict__ h,
                                                unsigned short* __restrict__ h_hi,
                                                unsigned short* __restrict__ h_lo)
{
    const int m0 = blockIdx.x * 64;
    const int n0 = blockIdx.y * 64;
    const int tx = threadIdx.x, ty = threadIdx.y;   // 16 x 16
    const int tid = ty * 16 + tx;

    __shared__ float As[64][68];   // [k][m]
    __shared__ float Bs[64][68];   // [k][n]

    for (int i = tid; i < 64 * 16; i += 256) {
        int r  = i >> 4;
        int k4 = i & 15;
        float4 v = *(const float4*)(x + (size_t)(m0 + r) * F_ + k4 * 4);
        As[k4*4+0][r] = v.x; As[k4*4+1][r] = v.y;
        As[k4*4+2][r] = v.z; As[k4*4+3][r] = v.w;
    }
    for (int i = tid; i < 64 * 16; i += 256) {
        int k  = i >> 4;
        int n4 = i & 15;
        *(float4*)&Bs[k][n4*4] = *(const float4*)(Win + (size_t)k * D_ + n0 + n4*4);
    }
    __syncthreads();

    float acc[4][4] = {};
    #pragma unroll 8
    for (int k = 0; k < 64; ++k) {
        float4 a = *(const float4*)&As[k][ty * 4];
        float4 b = *(const float4*)&Bs[k][tx * 4];
        float av[4] = {a.x, a.y, a.z, a.w};
        float bv[4] = {b.x, b.y, b.z, b.w};
        #pragma unroll
        for (int i = 0; i < 4; ++i)
            #pragma unroll
            for (int j = 0; j < 4; ++j)
                acc[i][j] += av[i] * bv[j];
    }

    float bv[4];
    #pragma unroll
    for (int j = 0; j < 4; ++j) bv[j] = bin[n0 + tx*4 + j];
    #pragma unroll
    for (int i = 0; i < 4; ++i) {
        int row = m0 + ty * 4 + i;
        float o[4];
        #pragma unroll
        for (int j = 0; j < 4; ++j) o[j] = acc[i][j] + bv[j];
        float4 ov = {o[0], o[1], o[2], o[3]};
        *(float4*)(h + (size_t)row * D_ + n0 + tx * 4) = ov;

        ushort4 hi4, lo4;
        unsigned short hh;
        hh = f2bf_rne(o[0]); hi4.x = hh; lo4.x = f2bf_rne(o[0] - bf2f(hh));
        hh = f2bf_rne(o[1]); hi4.y = hh; lo4.y = f2bf_rne(o[1] - bf2f(hh));
        hh = f2bf_rne(o[2]); hi4.z = hh; lo4.z = f2bf_rne(o[2] - bf2f(hh));
        hh = f2bf_rne(o[3]); hi4.w = hh; lo4.w = f2bf_rne(o[3] - bf2f(hh));
        *(ushort4*)(h_hi + (size_t)row * D_ + n0 + tx * 4) = hi4;
        *(ushort4*)(h_lo + (size_t)row * D_ + n0 + tx * 4) = lo4;
    }
}

// ---------------------------------------------------------------------------
// Kernel 1b: W prep — build Wc_{hi,lo}[s][n][k] (n-major, transposed) where
// n in [0,256) = Wd columns, n in [256,512) = Wtau columns.
// ---------------------------------------------------------------------------
__global__ __launch_bounds__(256) void k_wprep(const float* __restrict__ Wd,
                                               const float* __restrict__ Wt,
                                               unsigned short* __restrict__ Wc_hi,
                                               unsigned short* __restrict__ Wc_lo)
{
    const int n = blockIdx.x;          // 0..511
    const int s = blockIdx.y;
    const int k = threadIdx.x;         // 0..255
    float v;
    if (n < 256) v = Wd[(size_t)s * D_ * D_ + (size_t)k * D_ + n];
    else         v = Wt[(size_t)s * D_ * D_ + (size_t)k * D_ + (n - 256)];
    unsigned short hi = f2bf_rne(v);
    size_t o = ((size_t)s * 512 + n) * D_ + k;
    Wc_hi[o] = hi;
    Wc_lo[o] = f2bf_rne(v - bf2f(hi));
}

// ---------------------------------------------------------------------------
// Kernel 2: delta = softplus(h@Wd + bd) * sigmoid(h@Wtau)  — split-bf16 MFMA.
// Block: 128 rows x (64 delta cols + 64 paired tau cols). BK=32, K=256.
// 4 waves, each owns 32 rows x all 128 logical cols (delta/tau pair in-reg).
// ---------------------------------------------------------------------------
__global__ __launch_bounds__(256) void k_deltatau_mfma(
        const unsigned short* __restrict__ h_hi,
        const unsigned short* __restrict__ h_lo,
        const unsigned short* __restrict__ Wc_hi,
        const unsigned short* __restrict__ Wc_lo,
        const float* __restrict__ bd,
        float* __restrict__ delta)
{
    const int m0  = blockIdx.x * 128;
    const int e0  = blockIdx.y * 64;
    const int s   = blockIdx.z;
    const int tid  = threadIdx.x;
    const int wid  = tid >> 6;
    const int lane = tid & 63;
    const int l15  = lane & 15;
    const int quad = lane >> 4;
    const int r_in = lane >> 2;   // staging: row within 16-row chunk
    const int c_in = lane & 3;    // staging: 16B chunk within 64B row

    __shared__ unsigned short Ah[128 * 32];
    __shared__ unsigned short Al[128 * 32];
    __shared__ unsigned short Bh[128 * 32];
    __shared__ unsigned short Bl[128 * 32];

    const unsigned short* wh = Wc_hi + (size_t)s * 512 * D_;
    const unsigned short* wl = Wc_lo + (size_t)s * 512 * D_;

    f32x4 acc[2][8];
    #pragma unroll
    for (int i = 0; i < 2; ++i)
        #pragma unroll
        for (int j = 0; j < 8; ++j)
            acc[i][j] = (f32x4){0.f, 0.f, 0.f, 0.f};

    for (int k0 = 0; k0 < D_; k0 += 32) {
        // ---- stage A (h rows) and B (W rows), wave w handles rows [w*32, w*32+32)
        #pragma unroll
        for (int call = 0; call < 2; ++call) {
            const int base = wid * 32 + call * 16;      // base row of this 1KB call
            const int r    = base + r_in;               // this lane's row
            // A: global m = m0 + r, row-major [m][k]
            const size_t ga = (size_t)(m0 + r) * D_ + k0 + c_in * 8;
            async_copy16(h_hi + ga, &Ah[base * 32]);
            async_copy16(h_lo + ga, &Al[base * 32]);
            // B: logical nl = r; nl<64 -> delta col e0+nl, else tau col 256+e0+(nl-64)
            const int gn = (r < 64) ? (e0 + r) : (256 + e0 + (r - 64));
            const size_t gb = (size_t)gn * D_ + k0 + c_in * 8;
            async_copy16(wh + gb, &Bh[base * 32]);
            async_copy16(wl + gb, &Bl[base * 32]);
        }
        __syncthreads();

        bf16x8 bhf[8], blf[8];
        #pragma unroll
        for (int nj = 0; nj < 8; ++nj) {
            const int off = (nj * 16 + l15) * 32 + quad * 8;
            bhf[nj] = *(const bf16x8*)&Bh[off];
            blf[nj] = *(const bf16x8*)&Bl[off];
        }
        #pragma unroll
        for (int mi = 0; mi < 2; ++mi) {
            const int aoff = (wid * 32 + mi * 16 + l15) * 32 + quad * 8;
            bf16x8 ah = *(const bf16x8*)&Ah[aoff];
            bf16x8 al = *(const bf16x8*)&Al[aoff];
            #pragma unroll
            for (int nj = 0; nj < 8; ++nj) {
                acc[mi][nj] = __builtin_amdgcn_mfma_f32_16x16x32_bf16(ah, bhf[nj], acc[mi][nj], 0, 0, 0);
                acc[mi][nj] = __builtin_amdgcn_mfma_f32_16x16x32_bf16(ah, blf[nj], acc[mi][nj], 0, 0, 0);
                acc[mi][nj] = __builtin_amdgcn_mfma_f32_16x16x32_bf16(al, bhf[nj], acc[mi][nj], 0, 0, 0);
            }
        }
        __syncthreads();
    }

    // ---- epilogue: pair delta-acc (nj=j) with tau-acc (nj=j+4), fuse activations
    float* dout = delta + (size_t)s * BL_ * D_;
    #pragma unroll
    for (int mi = 0; mi < 2; ++mi) {
        #pragma unroll
        for (int j = 0; j < 4; ++j) {
            const int e = e0 + j * 16 + l15;
            const float bde = bd[s * D_ + e];
            #pragma unroll
            for (int r = 0; r < 4; ++r) {
                const int m = m0 + wid * 32 + mi * 16 + quad * 4 + r;
                const float pd = acc[mi][j][r] + bde;
                const float sp = fmaxf(pd, 0.f) + log1pf(__expf(-fabsf(pd)));
                const float sg = 1.f / (1.f + __expf(-acc[mi][j + 4][r]));
                dout[(size_t)m * D_ + e] = sp * sg;
            }
        }
    }
}

// ---------------------------------------------------------------------------
// Kernel 3: Bm = h @ WB   per s  (M=16384, K=256, N=16)
// ---------------------------------------------------------------------------
__global__ __launch_bounds__(256) void k_bm(const float* __restrict__ h,
                                            const float* __restrict__ WB,
                                            float* __restrict__ Bm)
{
    const int s   = blockIdx.y;
    const int tid = threadIdx.x;
    const int row = blockIdx.x * 16 + (tid >> 4);
    const int n   = tid & 15;
    const float* wb = WB + (size_t)s * D_ * N_;
    const float* hr = h + (size_t)row * D_;
    float acc = 0.f;
    #pragma unroll 4
    for (int k = 0; k < D_; k += 4) {
        float4 hv = *(const float4*)(hr + k);
        acc += hv.x * wb[(k+0)*N_ + n];
        acc += hv.y * wb[(k+1)*N_ + n];
        acc += hv.z * wb[(k+2)*N_ + n];
        acc += hv.w * wb[(k+3)*N_ + n];
    }
    Bm[((size_t)s * BL_ + row) * N_ + n] = acc;
}

// ---------------------------------------------------------------------------
// Kernel 4: recurrence over L for final state only.
// ---------------------------------------------------------------------------
__global__ __launch_bounds__(256) void k_scan(const float* __restrict__ delta,
                                              const float* __restrict__ h,
                                              const float* __restrict__ Bm,
                                              const float* __restrict__ A_log,
                                              float* __restrict__ states)
{
    const int d0 = blockIdx.x * 16;
    const int b  = blockIdx.y;
    const int s  = blockIdx.z;
    const int tid = threadIdx.x;
    const int dl = tid & 15;
    const int nl = tid >> 4;
    const int d  = d0 + dl;

    const float A = -__expf(A_log[((size_t)s * D_ + d) * N_ + nl]);

    const float* dptr = delta + ((size_t)s * BL_ + (size_t)b * L_) * D_ + d0;
    const float* hptr = h + ((size_t)b * L_) * D_ + d0;
    const float* bptr = Bm + ((size_t)s * BL_ + (size_t)b * L_) * N_;

    __shared__ float sd[8][16];
    __shared__ float sh[8][16];
    __shared__ float sb[8][16];

    float state = 0.f;
    for (int t0 = 0; t0 < L_; t0 += 8) {
        if (tid < 96) {
            int grp = tid >> 5;
            int i   = tid & 31;
            int tt  = i >> 2;
            int q   = i & 3;
            if (grp == 0) {
                *(float4*)&sd[tt][q*4] = *(const float4*)(dptr + (size_t)(t0+tt)*D_ + q*4);
            } else if (grp == 1) {
                *(float4*)&sh[tt][q*4] = *(const float4*)(hptr + (size_t)(t0+tt)*D_ + q*4);
            } else {
                *(float4*)&sb[tt][q*4] = *(const float4*)(bptr + (size_t)(t0+tt)*N_ + q*4);
            }
        }
        __syncthreads();
        #pragma unroll
        for (int tt = 0; tt < 8; ++tt) {
            float dlt = sd[tt][dl];
            float bx  = dlt * sb[tt][nl] * sh[tt][dl];
            state = __expf(dlt * A) * state + bx;
        }
        __syncthreads();
    }
    states[(((size_t)s * B_ + b) * D_ + d) * N_ + nl] = state;
}

// ---------------------------------------------------------------------------
// Kernel 5: final readout. One block per batch element b.
// ---------------------------------------------------------------------------
__global__ __launch_bounds__(256) void k_final(const float* __restrict__ h,
                                               const float* __restrict__ states,
                                               const float* __restrict__ WC,
                                               const float* __restrict__ Dp,
                                               const float* __restrict__ Wout,
                                               const float* __restrict__ ln_g,
                                               const float* __restrict__ ln_b,
                                               const float* __restrict__ W1,
                                               const float* __restrict__ b1,
                                               const float* __restrict__ W2,
                                               const float* __restrict__ b2,
                                               float* __restrict__ out)
{
    const int b   = blockIdx.x;
    const int tid = threadIdx.x;

    __shared__ float hl[D_];
    __shared__ float cm[S_][N_];
    __shared__ float ys[S_][D_];
    __shared__ float zv[D_];
    __shared__ float red1[256];
    __shared__ float red2[256];
    __shared__ float r1[H_];

    hl[tid] = h[((size_t)b * L_ + (L_ - 1)) * D_ + tid];
    __syncthreads();

    if (tid < S_ * N_) {
        int s = tid >> 4, n = tid & 15;
        float a = 0.f;
        for (int d = 0; d < D_; ++d) a += hl[d] * WC[((size_t)s * D_ + d) * N_ + n];
        cm[s][n] = a;
    }
    __syncthreads();

    for (int s = 0; s < S_; ++s) {
        const float* st = states + (((size_t)s * B_ + b) * D_ + tid) * N_;
        float a = 0.f;
        #pragma unroll
        for (int n = 0; n < N_; ++n) a += st[n] * cm[s][n];
        ys[s][tid] = a + hl[tid] * Dp[s * D_ + tid];
    }
    __syncthreads();

    float v;
    {
        float a = 0.f;
        for (int s = 0; s < S_; ++s) {
            const float* wo = Wout + (size_t)s * D_ * D_;
            for (int d = 0; d < D_; ++d) a += ys[s][d] * wo[(size_t)d * D_ + tid];
        }
        v = a * (1.f / S_);
    }

    red1[tid] = v;
    red2[tid] = v * v;
    __syncthreads();
    for (int off = 128; off > 0; off >>= 1) {
        if (tid < off) { red1[tid] += red1[tid + off]; red2[tid] += red2[tid + off]; }
        __syncthreads();
    }
    const float mu  = red1[0] * (1.f / D_);
    const float var = red2[0] * (1.f / D_) - mu * mu;
    const float z = (v - mu) * rsqrtf(var + EPS_) * ln_g[tid] + ln_b[tid];
    zv[tid] = z;
    __syncthreads();

    if (tid < H_) {
        float a = b1[tid];
        for (int e = 0; e < D_; ++e) a += zv[e] * W1[(size_t)e * H_ + tid];
        r1[tid] = fmaxf(a, 0.f);
    }
    __syncthreads();
    if (tid == 0) {
        float a = b2[0];
        for (int j = 0; j < H_; ++j) a += r1[j] * W2[j];
        out[b] = a;
    }
}

// ---------------------------------------------------------------------------
extern "C" void kernel_launch(void* const* d_in, const int* in_sizes, int n_in,
                              void* d_out, int out_size, void* d_ws, size_t ws_size,
                              hipStream_t stream)
{
    const float* x     = (const float*)d_in[0];
    const float* Win   = (const float*)d_in[1];
    const float* bin   = (const float*)d_in[2];
    const float* Wd    = (const float*)d_in[3];
    const float* bd    = (const float*)d_in[4];
    const float* WB    = (const float*)d_in[5];
    const float* WC    = (const float*)d_in[6];
    const float* Wtau  = (const float*)d_in[7];
    const float* A_log = (const float*)d_in[8];
    const float* Dp    = (const float*)d_in[9];
    const float* Wout  = (const float*)d_in[10];
    const float* ln_g  = (const float*)d_in[11];
    const float* ln_b  = (const float*)d_in[12];
    const float* W1    = (const float*)d_in[13];
    const float* b1    = (const float*)d_in[14];
    const float* W2    = (const float*)d_in[15];
    const float* b2    = (const float*)d_in[16];
    float* out = (float*)d_out;

    char* ws = (char*)d_ws;
    const size_t MB = 1024 * 1024;
    float*          h      = (float*)(ws);                    // 16 MiB
    float*          delta  = (float*)(ws + 16 * MB);          // 32 MiB
    float*          Bm     = (float*)(ws + 48 * MB);          //  2 MiB
    float*          states = (float*)(ws + 50 * MB);          //  0.5 MiB
    unsigned short* h_hi   = (unsigned short*)(ws + 51 * MB); //  8 MiB
    unsigned short* h_lo   = (unsigned short*)(ws + 59 * MB); //  8 MiB
    unsigned short* Wc_hi  = (unsigned short*)(ws + 67 * MB); //  0.5 MiB
    unsigned short* Wc_lo  = (unsigned short*)(ws + (67 * MB + 512 * 1024)); // 0.5 MiB

    dim3 blk2d(16, 16);
    hipLaunchKernelGGL(k_wprep,         dim3(512, 2),            dim3(256), 0, stream, Wd, Wtau, Wc_hi, Wc_lo);
    hipLaunchKernelGGL(k_inproj,        dim3(BL_/64, D_/64),     blk2d,     0, stream, x, Win, bin, h, h_hi, h_lo);
    hipLaunchKernelGGL(k_deltatau_mfma, dim3(BL_/128, D_/64, S_),dim3(256), 0, stream, h_hi, h_lo, Wc_hi, Wc_lo, bd, delta);
    hipLaunchKernelGGL(k_bm,            dim3(BL_/16, S_),        dim3(256), 0, stream, h, WB, Bm);
    hipLaunchKernelGGL(k_scan,          dim3(D_/16, B_, S_),     dim3(256), 0, stream, delta, h, Bm, A_log, states);
    hipLaunchKernelGGL(k_final,         dim3(B_),                dim3(256), 0, stream,
                       h, states, WC, Dp, Wout, ln_g, ln_b, W1, b1, W2, b2, out);
}

// Round 3
// 238.819 us; speedup vs baseline: 1.5018x; 1.2287x over previous
//
#include <hip/hip_runtime.h>
#include <hip/hip_bf16.h>
#include <math.h>

#define B_   16
#define L_   1024
#define F_   64
#define D_   256
#define S_   2
#define N_   16
#define H_   32
#define EPS_ 1e-5f
#define BL_  (B_*L_)
#define NCH_ 4          // t-chunks for the parallel scan
#define TC_  (L_/NCH_)  // 256 timesteps per chunk

typedef __attribute__((ext_vector_type(8))) short  bf16x8;
typedef __attribute__((ext_vector_type(4))) float  f32x4;

typedef const __attribute__((address_space(1))) void* gas_ptr;
typedef __attribute__((address_space(3))) void*       las_ptr;

__device__ inline void async_copy16(const void* g, void* l) {
    __builtin_amdgcn_global_load_lds((gas_ptr)g, (las_ptr)l, 16, 0, 0);
}

__device__ inline unsigned short f2bf_rne(float x) {
    union { float f; unsigned u; } v; v.f = x;
    unsigned r = v.u + 0x7fff + ((v.u >> 16) & 1);
    return (unsigned short)(r >> 16);
}
__device__ inline float bf2f(unsigned short h) {
    union { float f; unsigned u; } v; v.u = ((unsigned)h) << 16;
    return v.f;
}

// ---------------------------------------------------------------------------
// Kernel 1: h = x @ W_in + b_in   (M=BL=16384, K=64, N=256)
// Also emits split-bf16 h_hi/h_lo for the MFMA deltatau GEMM.
// ---------------------------------------------------------------------------
__global__ __launch_bounds__(256) void k_inproj(const float* __restrict__ x,
                                                const float* __restrict__ Win,
                                                const float* __restrict__ bin,
                                                float* __restrict__ h,
                                                unsigned short* __restrict__ h_hi,
                                                unsigned short* __restrict__ h_lo)
{
    const int m0 = blockIdx.x * 64;
    const int n0 = blockIdx.y * 64;
    const int tx = threadIdx.x, ty = threadIdx.y;   // 16 x 16
    const int tid = ty * 16 + tx;

    __shared__ float As[64][68];   // [k][m]
    __shared__ float Bs[64][68];   // [k][n]

    for (int i = tid; i < 64 * 16; i += 256) {
        int r  = i >> 4;
        int k4 = i & 15;
        float4 v = *(const float4*)(x + (size_t)(m0 + r) * F_ + k4 * 4);
        As[k4*4+0][r] = v.x; As[k4*4+1][r] = v.y;
        As[k4*4+2][r] = v.z; As[k4*4+3][r] = v.w;
    }
    for (int i = tid; i < 64 * 16; i += 256) {
        int k  = i >> 4;
        int n4 = i & 15;
        *(float4*)&Bs[k][n4*4] = *(const float4*)(Win + (size_t)k * D_ + n0 + n4*4);
    }
    __syncthreads();

    float acc[4][4] = {};
    #pragma unroll 8
    for (int k = 0; k < 64; ++k) {
        float4 a = *(const float4*)&As[k][ty * 4];
        float4 b = *(const float4*)&Bs[k][tx * 4];
        float av[4] = {a.x, a.y, a.z, a.w};
        float bv[4] = {b.x, b.y, b.z, b.w};
        #pragma unroll
        for (int i = 0; i < 4; ++i)
            #pragma unroll
            for (int j = 0; j < 4; ++j)
                acc[i][j] += av[i] * bv[j];
    }

    float bv[4];
    #pragma unroll
    for (int j = 0; j < 4; ++j) bv[j] = bin[n0 + tx*4 + j];
    #pragma unroll
    for (int i = 0; i < 4; ++i) {
        int row = m0 + ty * 4 + i;
        float o[4];
        #pragma unroll
        for (int j = 0; j < 4; ++j) o[j] = acc[i][j] + bv[j];
        float4 ov = {o[0], o[1], o[2], o[3]};
        *(float4*)(h + (size_t)row * D_ + n0 + tx * 4) = ov;

        ushort4 hi4, lo4;
        unsigned short hh;
        hh = f2bf_rne(o[0]); hi4.x = hh; lo4.x = f2bf_rne(o[0] - bf2f(hh));
        hh = f2bf_rne(o[1]); hi4.y = hh; lo4.y = f2bf_rne(o[1] - bf2f(hh));
        hh = f2bf_rne(o[2]); hi4.z = hh; lo4.z = f2bf_rne(o[2] - bf2f(hh));
        hh = f2bf_rne(o[3]); hi4.w = hh; lo4.w = f2bf_rne(o[3] - bf2f(hh));
        *(ushort4*)(h_hi + (size_t)row * D_ + n0 + tx * 4) = hi4;
        *(ushort4*)(h_lo + (size_t)row * D_ + n0 + tx * 4) = lo4;
    }
}

// ---------------------------------------------------------------------------
// Kernel 1b: W prep — build Wc_{hi,lo}[s][n][k] (n-major, transposed) where
// n in [0,256) = Wd columns, n in [256,512) = Wtau columns.
// ---------------------------------------------------------------------------
__global__ __launch_bounds__(256) void k_wprep(const float* __restrict__ Wd,
                                               const float* __restrict__ Wt,
                                               unsigned short* __restrict__ Wc_hi,
                                               unsigned short* __restrict__ Wc_lo)
{
    const int n = blockIdx.x;          // 0..511
    const int s = blockIdx.y;
    const int k = threadIdx.x;         // 0..255
    float v;
    if (n < 256) v = Wd[(size_t)s * D_ * D_ + (size_t)k * D_ + n];
    else         v = Wt[(size_t)s * D_ * D_ + (size_t)k * D_ + (n - 256)];
    unsigned short hi = f2bf_rne(v);
    size_t o = ((size_t)s * 512 + n) * D_ + k;
    Wc_hi[o] = hi;
    Wc_lo[o] = f2bf_rne(v - bf2f(hi));
}

// ---------------------------------------------------------------------------
// Kernel 1c: WBeff[s] = Win @ WB[s]  (F x N), bbias[s][n] = b_in . WB[s][:,n]
// ---------------------------------------------------------------------------
__global__ __launch_bounds__(256) void k_wbeff(const float* __restrict__ Win,
                                               const float* __restrict__ bin,
                                               const float* __restrict__ WB,
                                               float* __restrict__ WBeff,
                                               float* __restrict__ bbias)
{
    const int s   = blockIdx.y;
    const int idx = blockIdx.x * 256 + threadIdx.x;   // 0..1023
    const int f   = idx >> 4;
    const int n   = idx & 15;
    const float* wb = WB + (size_t)s * D_ * N_;
    float a = 0.f;
    for (int d = 0; d < D_; ++d) a += Win[(size_t)f * D_ + d] * wb[(size_t)d * N_ + n];
    WBeff[((size_t)s * F_ + f) * N_ + n] = a;
    if (blockIdx.x == 0 && threadIdx.x < N_) {
        float bbv = 0.f;
        for (int d = 0; d < D_; ++d) bbv += bin[d] * wb[(size_t)d * N_ + threadIdx.x];
        bbias[s * N_ + threadIdx.x] = bbv;
    }
}

// ---------------------------------------------------------------------------
// Kernel 2: delta = softplus(h@Wd + bd) * sigmoid(h@Wtau)  — split-bf16 MFMA.
// ---------------------------------------------------------------------------
__global__ __launch_bounds__(256) void k_deltatau_mfma(
        const unsigned short* __restrict__ h_hi,
        const unsigned short* __restrict__ h_lo,
        const unsigned short* __restrict__ Wc_hi,
        const unsigned short* __restrict__ Wc_lo,
        const float* __restrict__ bd,
        float* __restrict__ delta)
{
    const int m0  = blockIdx.x * 128;
    const int e0  = blockIdx.y * 64;
    const int s   = blockIdx.z;
    const int tid  = threadIdx.x;
    const int wid  = tid >> 6;
    const int lane = tid & 63;
    const int l15  = lane & 15;
    const int quad = lane >> 4;
    const int r_in = lane >> 2;
    const int c_in = lane & 3;

    __shared__ unsigned short Ah[128 * 32];
    __shared__ unsigned short Al[128 * 32];
    __shared__ unsigned short Bh[128 * 32];
    __shared__ unsigned short Bl[128 * 32];

    const unsigned short* wh = Wc_hi + (size_t)s * 512 * D_;
    const unsigned short* wl = Wc_lo + (size_t)s * 512 * D_;

    f32x4 acc[2][8];
    #pragma unroll
    for (int i = 0; i < 2; ++i)
        #pragma unroll
        for (int j = 0; j < 8; ++j)
            acc[i][j] = (f32x4){0.f, 0.f, 0.f, 0.f};

    for (int k0 = 0; k0 < D_; k0 += 32) {
        #pragma unroll
        for (int call = 0; call < 2; ++call) {
            const int base = wid * 32 + call * 16;
            const int r    = base + r_in;
            const size_t ga = (size_t)(m0 + r) * D_ + k0 + c_in * 8;
            async_copy16(h_hi + ga, &Ah[base * 32]);
            async_copy16(h_lo + ga, &Al[base * 32]);
            const int gn = (r < 64) ? (e0 + r) : (256 + e0 + (r - 64));
            const size_t gb = (size_t)gn * D_ + k0 + c_in * 8;
            async_copy16(wh + gb, &Bh[base * 32]);
            async_copy16(wl + gb, &Bl[base * 32]);
        }
        __syncthreads();

        bf16x8 bhf[8], blf[8];
        #pragma unroll
        for (int nj = 0; nj < 8; ++nj) {
            const int off = (nj * 16 + l15) * 32 + quad * 8;
            bhf[nj] = *(const bf16x8*)&Bh[off];
            blf[nj] = *(const bf16x8*)&Bl[off];
        }
        #pragma unroll
        for (int mi = 0; mi < 2; ++mi) {
            const int aoff = (wid * 32 + mi * 16 + l15) * 32 + quad * 8;
            bf16x8 ah = *(const bf16x8*)&Ah[aoff];
            bf16x8 al = *(const bf16x8*)&Al[aoff];
            #pragma unroll
            for (int nj = 0; nj < 8; ++nj) {
                acc[mi][nj] = __builtin_amdgcn_mfma_f32_16x16x32_bf16(ah, bhf[nj], acc[mi][nj], 0, 0, 0);
                acc[mi][nj] = __builtin_amdgcn_mfma_f32_16x16x32_bf16(ah, blf[nj], acc[mi][nj], 0, 0, 0);
                acc[mi][nj] = __builtin_amdgcn_mfma_f32_16x16x32_bf16(al, bhf[nj], acc[mi][nj], 0, 0, 0);
            }
        }
        __syncthreads();
    }

    float* dout = delta + (size_t)s * BL_ * D_;
    #pragma unroll
    for (int mi = 0; mi < 2; ++mi) {
        #pragma unroll
        for (int j = 0; j < 4; ++j) {
            const int e = e0 + j * 16 + l15;
            const float bde = bd[s * D_ + e];
            #pragma unroll
            for (int r = 0; r < 4; ++r) {
                const int m = m0 + wid * 32 + mi * 16 + quad * 4 + r;
                const float pd = acc[mi][j][r] + bde;
                const float sp = fmaxf(pd, 0.f) + log1pf(__expf(-fabsf(pd)));
                const float sg = 1.f / (1.f + __expf(-acc[mi][j + 4][r]));
                dout[(size_t)m * D_ + e] = sp * sg;
            }
        }
    }
}

// ---------------------------------------------------------------------------
// Kernel 3: Bm = x @ WBeff + bbias   per s  (M=16384, K=64, N=16)
// ---------------------------------------------------------------------------
__global__ __launch_bounds__(256) void k_bm(const float* __restrict__ x,
                                            const float* __restrict__ WBeff,
                                            const float* __restrict__ bbias,
                                            float* __restrict__ Bm)
{
    const int s   = blockIdx.y;
    const int tid = threadIdx.x;
    const int row = blockIdx.x * 16 + (tid >> 4);
    const int n   = tid & 15;
    const float* we = WBeff + (size_t)s * F_ * N_;
    const float* xr = x + (size_t)row * F_;
    float acc = bbias[s * N_ + n];
    #pragma unroll 4
    for (int k = 0; k < F_; k += 4) {
        float4 xv = *(const float4*)(xr + k);
        acc += xv.x * we[(k+0)*N_ + n];
        acc += xv.y * we[(k+1)*N_ + n];
        acc += xv.z * we[(k+2)*N_ + n];
        acc += xv.w * we[(k+3)*N_ + n];
    }
    Bm[((size_t)s * BL_ + row) * N_ + n] = acc;
}

// ---------------------------------------------------------------------------
// Kernel 4a: parallel scan, stage 1. Since A is constant per (s,d,n) chain,
// the decay over a span is exp(A * sum(delta)). Each block handles one
// (s, b, 16-d tile, t-chunk of 256) and computes, walking t backward:
//   part[d][n] = sum_t delta_t*h_t*Bm_t[n]*exp(A * suffix_within_chunk(t))
//   csum[d]    = sum_t delta_t
// ---------------------------------------------------------------------------
__global__ __launch_bounds__(256) void k_scan_part(const float* __restrict__ delta,
                                                   const float* __restrict__ h,
                                                   const float* __restrict__ Bm,
                                                   const float* __restrict__ A_log,
                                                   float* __restrict__ part,
                                                   float* __restrict__ csum)
{
    const int dtile = blockIdx.x >> 2;          // 0..15
    const int c     = blockIdx.x & 3;           // chunk 0..3
    const int b     = blockIdx.y;
    const int s     = blockIdx.z;
    const int d0    = dtile * 16;
    const int tc0   = c * TC_;
    const int tid   = threadIdx.x;
    const int dl    = tid & 15;
    const int nl    = tid >> 4;
    const int d     = d0 + dl;

    const float A = -__expf(A_log[((size_t)s * D_ + d) * N_ + nl]);

    const float* dptr = delta + ((size_t)s * BL_ + (size_t)b * L_) * D_ + d0;
    const float* hptr = h + ((size_t)b * L_) * D_ + d0;
    const float* bptr = Bm + ((size_t)s * BL_ + (size_t)b * L_) * N_;

    __shared__ float sd[32][16];
    __shared__ float sh[32][16];
    __shared__ float sb[32][16];

    float state = 0.f;
    float accs  = 0.f;   // running suffix sum of delta (exclusive), per-d

    for (int sc = (TC_/32) - 1; sc >= 0; --sc) {
        // stage 32 timesteps x 16 floats for each of the 3 arrays
        for (int i = tid; i < 384; i += 256) {
            int grp = i >> 7;        // 0: delta, 1: h, 2: Bm
            int idx = i & 127;
            int tt  = idx >> 2;
            int q   = idx & 3;
            int tg  = tc0 + sc * 32 + tt;
            if (grp == 0)
                *(float4*)&sd[tt][q*4] = *(const float4*)(dptr + (size_t)tg * D_ + q*4);
            else if (grp == 1)
                *(float4*)&sh[tt][q*4] = *(const float4*)(hptr + (size_t)tg * D_ + q*4);
            else
                *(float4*)&sb[tt][q*4] = *(const float4*)(bptr + (size_t)tg * N_ + q*4);
        }
        __syncthreads();
        #pragma unroll
        for (int tt = 31; tt >= 0; --tt) {
            float dlt = sd[tt][dl];
            float e   = __expf(A * accs);
            state += dlt * sh[tt][dl] * sb[tt][nl] * e;
            accs  += dlt;
        }
        __syncthreads();
    }

    part[((((size_t)s * B_ + b) * NCH_ + c) * D_ + d) * N_ + nl] = state;
    if (nl == 0)
        csum[(((size_t)s * B_ + b) * NCH_ + c) * D_ + d] = accs;
}

// ---------------------------------------------------------------------------
// Kernel 4b: combine chunks: state = sum_c exp(A * tail_c) * part_c,
// tail_c = sum of csum over chunks after c.
// ---------------------------------------------------------------------------
__global__ __launch_bounds__(256) void k_scan_comb(const float* __restrict__ part,
                                                   const float* __restrict__ csum,
                                                   const float* __restrict__ A_log,
                                                   float* __restrict__ states)
{
    const int b   = blockIdx.y;
    const int s   = blockIdx.z;
    const int tid = threadIdx.x;
    const int dl  = tid & 15;
    const int nl  = tid >> 4;
    const int d   = blockIdx.x * 16 + dl;

    const float A = -__expf(A_log[((size_t)s * D_ + d) * N_ + nl]);

    const size_t cbase = ((size_t)s * B_ + b) * NCH_;
    float cs[NCH_];
    #pragma unroll
    for (int c = 0; c < NCH_; ++c) cs[c] = csum[(cbase + c) * D_ + d];

    float state = 0.f;
    float tail = 0.f;
    #pragma unroll
    for (int c = NCH_ - 1; c >= 0; --c) {
        float p = part[((cbase + c) * D_ + d) * N_ + nl];
        state += __expf(A * tail) * p;
        tail  += cs[c];
    }
    states[(((size_t)s * B_ + b) * D_ + d) * N_ + nl] = state;
}

// ---------------------------------------------------------------------------
// Kernel 5: final readout. One block per batch element b.
// ---------------------------------------------------------------------------
__global__ __launch_bounds__(256) void k_final(const float* __restrict__ h,
                                               const float* __restrict__ states,
                                               const float* __restrict__ WC,
                                               const float* __restrict__ Dp,
                                               const float* __restrict__ Wout,
                                               const float* __restrict__ ln_g,
                                               const float* __restrict__ ln_b,
                                               const float* __restrict__ W1,
                                               const float* __restrict__ b1,
                                               const float* __restrict__ W2,
                                               const float* __restrict__ b2,
                                               float* __restrict__ out)
{
    const int b   = blockIdx.x;
    const int tid = threadIdx.x;

    __shared__ float hl[D_];
    __shared__ float cm[S_][N_];
    __shared__ float ys[S_][D_];
    __shared__ float zv[D_];
    __shared__ float red1[256];
    __shared__ float red2[256];
    __shared__ float r1[H_];

    hl[tid] = h[((size_t)b * L_ + (L_ - 1)) * D_ + tid];
    __syncthreads();

    if (tid < S_ * N_) {
        int s = tid >> 4, n = tid & 15;
        float a = 0.f;
        for (int d = 0; d < D_; ++d) a += hl[d] * WC[((size_t)s * D_ + d) * N_ + n];
        cm[s][n] = a;
    }
    __syncthreads();

    for (int s = 0; s < S_; ++s) {
        const float* st = states + (((size_t)s * B_ + b) * D_ + tid) * N_;
        float a = 0.f;
        #pragma unroll
        for (int n = 0; n < N_; ++n) a += st[n] * cm[s][n];
        ys[s][tid] = a + hl[tid] * Dp[s * D_ + tid];
    }
    __syncthreads();

    float v;
    {
        float a = 0.f;
        for (int s = 0; s < S_; ++s) {
            const float* wo = Wout + (size_t)s * D_ * D_;
            for (int d = 0; d < D_; ++d) a += ys[s][d] * wo[(size_t)d * D_ + tid];
        }
        v = a * (1.f / S_);
    }

    red1[tid] = v;
    red2[tid] = v * v;
    __syncthreads();
    for (int off = 128; off > 0; off >>= 1) {
        if (tid < off) { red1[tid] += red1[tid + off]; red2[tid] += red2[tid + off]; }
        __syncthreads();
    }
    const float mu  = red1[0] * (1.f / D_);
    const float var = red2[0] * (1.f / D_) - mu * mu;
    const float z = (v - mu) * rsqrtf(var + EPS_) * ln_g[tid] + ln_b[tid];
    zv[tid] = z;
    __syncthreads();

    if (tid < H_) {
        float a = b1[tid];
        for (int e = 0; e < D_; ++e) a += zv[e] * W1[(size_t)e * H_ + tid];
        r1[tid] = fmaxf(a, 0.f);
    }
    __syncthreads();
    if (tid == 0) {
        float a = b2[0];
        for (int j = 0; j < H_; ++j) a += r1[j] * W2[j];
        out[b] = a;
    }
}

// ---------------------------------------------------------------------------
extern "C" void kernel_launch(void* const* d_in, const int* in_sizes, int n_in,
                              void* d_out, int out_size, void* d_ws, size_t ws_size,
                              hipStream_t stream)
{
    const float* x     = (const float*)d_in[0];
    const float* Win   = (const float*)d_in[1];
    const float* bin   = (const float*)d_in[2];
    const float* Wd    = (const float*)d_in[3];
    const float* bd    = (const float*)d_in[4];
    const float* WB    = (const float*)d_in[5];
    const float* WC    = (const float*)d_in[6];
    const float* Wtau  = (const float*)d_in[7];
    const float* A_log = (const float*)d_in[8];
    const float* Dp    = (const float*)d_in[9];
    const float* Wout  = (const float*)d_in[10];
    const float* ln_g  = (const float*)d_in[11];
    const float* ln_b  = (const float*)d_in[12];
    const float* W1    = (const float*)d_in[13];
    const float* b1    = (const float*)d_in[14];
    const float* W2    = (const float*)d_in[15];
    const float* b2    = (const float*)d_in[16];
    float* out = (float*)d_out;

    char* ws = (char*)d_ws;
    const size_t MB = 1024 * 1024;
    float*          h      = (float*)(ws);                        // 16 MiB
    float*          delta  = (float*)(ws + 16 * MB);              // 32 MiB
    float*          Bm     = (float*)(ws + 48 * MB);              //  2 MiB
    float*          states = (float*)(ws + 50 * MB);              //  0.5 MiB
    unsigned short* h_hi   = (unsigned short*)(ws + 51 * MB);     //  8 MiB
    unsigned short* h_lo   = (unsigned short*)(ws + 59 * MB);     //  8 MiB
    unsigned short* Wc_hi  = (unsigned short*)(ws + 67 * MB);     //  0.5 MiB
    unsigned short* Wc_lo  = (unsigned short*)(ws + 67 * MB + 512 * 1024);
    float*          part   = (float*)(ws + 68 * MB);              //  2 MiB
    float*          csum   = (float*)(ws + 70 * MB);              //  0.5 MiB
    float*          WBeff  = (float*)(ws + 70 * MB + 512 * 1024); //  8 KiB
    float*          bbias  = (float*)(ws + 70 * MB + 640 * 1024); //  128 B

    dim3 blk2d(16, 16);
    hipLaunchKernelGGL(k_wprep,         dim3(512, 2),               dim3(256), 0, stream, Wd, Wtau, Wc_hi, Wc_lo);
    hipLaunchKernelGGL(k_wbeff,         dim3(4, S_),                dim3(256), 0, stream, Win, bin, WB, WBeff, bbias);
    hipLaunchKernelGGL(k_inproj,        dim3(BL_/64, D_/64),        blk2d,     0, stream, x, Win, bin, h, h_hi, h_lo);
    hipLaunchKernelGGL(k_deltatau_mfma, dim3(BL_/128, D_/64, S_),   dim3(256), 0, stream, h_hi, h_lo, Wc_hi, Wc_lo, bd, delta);
    hipLaunchKernelGGL(k_bm,            dim3(BL_/16, S_),           dim3(256), 0, stream, x, WBeff, bbias, Bm);
    hipLaunchKernelGGL(k_scan_part,     dim3((D_/16)*NCH_, B_, S_), dim3(256), 0, stream, delta, h, Bm, A_log, part, csum);
    hipLaunchKernelGGL(k_scan_comb,     dim3(D_/16, B_, S_),        dim3(256), 0, stream, part, csum, A_log, states);
    hipLaunchKernelGGL(k_final,         dim3(B_),                   dim3(256), 0, stream,
                       h, states, WC, Dp, Wout, ln_g, ln_b, W1, b1, W2, b2, out);
}

// Round 4
// 217.382 us; speedup vs baseline: 1.6499x; 1.0986x over previous
//
#include <hip/hip_runtime.h>
#include <hip/hip_bf16.h>
#include <math.h>

#define B_   16
#define L_   1024
#define F_   64
#define D_   256
#define S_   2
#define N_   16
#define H_   32
#define EPS_ 1e-5f
#define BL_  (B_*L_)
#define NCH_ 4          // t-chunks for the parallel scan
#define TC_  (L_/NCH_)  // 256 timesteps per chunk

typedef __attribute__((ext_vector_type(8))) short  bf16x8;
typedef __attribute__((ext_vector_type(4))) float  f32x4;

typedef const __attribute__((address_space(1))) void* gas_ptr;
typedef __attribute__((address_space(3))) void*       las_ptr;

__device__ inline void async_copy16(const void* g, void* l) {
    __builtin_amdgcn_global_load_lds((gas_ptr)g, (las_ptr)l, 16, 0, 0);
}

__device__ inline unsigned short f2bf_rne(float x) {
    union { float f; unsigned u; } v; v.f = x;
    unsigned r = v.u + 0x7fff + ((v.u >> 16) & 1);
    return (unsigned short)(r >> 16);
}
__device__ inline float bf2f(unsigned short h) {
    union { float f; unsigned u; } v; v.u = ((unsigned)h) << 16;
    return v.f;
}

// ---------------------------------------------------------------------------
// Kernel 0: split x into bf16 hi/lo  (BL*F = 1M elements)
// ---------------------------------------------------------------------------
__global__ __launch_bounds__(256) void k_xsplit(const float* __restrict__ x,
                                                unsigned short* __restrict__ xh,
                                                unsigned short* __restrict__ xl)
{
    const int i = (blockIdx.x * 256 + threadIdx.x) * 4;
    float4 v = *(const float4*)(x + i);
    ushort4 h4, l4;
    unsigned short hh;
    hh = f2bf_rne(v.x); h4.x = hh; l4.x = f2bf_rne(v.x - bf2f(hh));
    hh = f2bf_rne(v.y); h4.y = hh; l4.y = f2bf_rne(v.y - bf2f(hh));
    hh = f2bf_rne(v.z); h4.z = hh; l4.z = f2bf_rne(v.z - bf2f(hh));
    hh = f2bf_rne(v.w); h4.w = hh; l4.w = f2bf_rne(v.w - bf2f(hh));
    *(ushort4*)(xh + i) = h4;
    *(ushort4*)(xl + i) = l4;
}

// ---------------------------------------------------------------------------
// Kernel 1: h = x @ W_in + b_in   (M=BL=16384, K=64, N=256)  — fp32, for
// the scan (h_t) and the final readout (h last). No bf16 emission anymore.
// ---------------------------------------------------------------------------
__global__ __launch_bounds__(256) void k_inproj(const float* __restrict__ x,
                                                const float* __restrict__ Win,
                                                const float* __restrict__ bin,
                                                float* __restrict__ h)
{
    const int m0 = blockIdx.x * 64;
    const int n0 = blockIdx.y * 64;
    const int tx = threadIdx.x, ty = threadIdx.y;   // 16 x 16
    const int tid = ty * 16 + tx;

    __shared__ float As[64][68];   // [k][m]
    __shared__ float Bs[64][68];   // [k][n]

    for (int i = tid; i < 64 * 16; i += 256) {
        int r  = i >> 4;
        int k4 = i & 15;
        float4 v = *(const float4*)(x + (size_t)(m0 + r) * F_ + k4 * 4);
        As[k4*4+0][r] = v.x; As[k4*4+1][r] = v.y;
        As[k4*4+2][r] = v.z; As[k4*4+3][r] = v.w;
    }
    for (int i = tid; i < 64 * 16; i += 256) {
        int k  = i >> 4;
        int n4 = i & 15;
        *(float4*)&Bs[k][n4*4] = *(const float4*)(Win + (size_t)k * D_ + n0 + n4*4);
    }
    __syncthreads();

    float acc[4][4] = {};
    #pragma unroll 8
    for (int k = 0; k < 64; ++k) {
        float4 a = *(const float4*)&As[k][ty * 4];
        float4 b = *(const float4*)&Bs[k][tx * 4];
        float av[4] = {a.x, a.y, a.z, a.w};
        float bv[4] = {b.x, b.y, b.z, b.w};
        #pragma unroll
        for (int i = 0; i < 4; ++i)
            #pragma unroll
            for (int j = 0; j < 4; ++j)
                acc[i][j] += av[i] * bv[j];
    }

    float bv[4];
    #pragma unroll
    for (int j = 0; j < 4; ++j) bv[j] = bin[n0 + tx*4 + j];
    #pragma unroll
    for (int i = 0; i < 4; ++i) {
        int row = m0 + ty * 4 + i;
        float4 o;
        o.x = acc[i][0] + bv[0];
        o.y = acc[i][1] + bv[1];
        o.z = acc[i][2] + bv[2];
        o.w = acc[i][3] + bv[3];
        *(float4*)(h + (size_t)row * D_ + n0 + tx * 4) = o;
    }
}

// ---------------------------------------------------------------------------
// Kernel 1b: Weff[s][n][f] = sum_d Win[f][d] * W[s][d][e]  (n-major, K=64),
// n in [0,256) = Wd cols (e=n), n in [256,512) = Wtau cols (e=n-256).
// bias_eff[s][n] = b_in . W[s][:,e]  (+ bd for delta rows).
// ---------------------------------------------------------------------------
__global__ __launch_bounds__(64) void k_weff(const float* __restrict__ Win,
                                             const float* __restrict__ bin,
                                             const float* __restrict__ Wd,
                                             const float* __restrict__ bd,
                                             const float* __restrict__ Wt,
                                             unsigned short* __restrict__ Weff_hi,
                                             unsigned short* __restrict__ Weff_lo,
                                             float* __restrict__ bias_eff)
{
    const int n = blockIdx.x;          // 0..511
    const int s = blockIdx.y;
    const int f = threadIdx.x;         // 0..63
    __shared__ float col[D_];
    const float* W = (n < 256) ? (Wd + (size_t)s * D_ * D_) : (Wt + (size_t)s * D_ * D_);
    const int e = (n < 256) ? n : (n - 256);
    for (int d = f; d < D_; d += 64) col[d] = W[(size_t)d * D_ + e];
    __syncthreads();
    float a = 0.f;
    for (int d = 0; d < D_; ++d) a += Win[(size_t)f * D_ + d] * col[d];
    unsigned short hi = f2bf_rne(a);
    size_t o = ((size_t)s * 512 + n) * F_ + f;
    Weff_hi[o] = hi;
    Weff_lo[o] = f2bf_rne(a - bf2f(hi));
    if (f == 0) {
        float bb = 0.f;
        for (int d = 0; d < D_; ++d) bb += bin[d] * col[d];
        if (n < 256) bb += bd[s * D_ + e];
        bias_eff[s * 512 + n] = bb;
    }
}

// ---------------------------------------------------------------------------
// Kernel 1c: WBeff[s] = Win @ WB[s]  (F x N), bbias[s][n] = b_in . WB[s][:,n]
// ---------------------------------------------------------------------------
__global__ __launch_bounds__(256) void k_wbeff(const float* __restrict__ Win,
                                               const float* __restrict__ bin,
                                               const float* __restrict__ WB,
                                               float* __restrict__ WBeff,
                                               float* __restrict__ bbias)
{
    const int s   = blockIdx.y;
    const int idx = blockIdx.x * 256 + threadIdx.x;   // 0..1023
    const int f   = idx >> 4;
    const int n   = idx & 15;
    const float* wb = WB + (size_t)s * D_ * N_;
    float a = 0.f;
    for (int d = 0; d < D_; ++d) a += Win[(size_t)f * D_ + d] * wb[(size_t)d * N_ + n];
    WBeff[((size_t)s * F_ + f) * N_ + n] = a;
    if (blockIdx.x == 0 && threadIdx.x < N_) {
        float bbv = 0.f;
        for (int d = 0; d < D_; ++d) bbv += bin[d] * wb[(size_t)d * N_ + threadIdx.x];
        bbias[s * N_ + threadIdx.x] = bbv;
    }
}

// ---------------------------------------------------------------------------
// Kernel 2: delta = softplus(x@Weffd + bias_d) * sigmoid(x@Wefft + bias_t)
// split-bf16 MFMA, K=64 (composed weights). Block: 128 m-rows x 64 e-cols
// (delta) + 64 paired tau cols. LDS chunk-swizzled: physical 16B chunk
// = (logical + (row>>1)) & 3  -> conflict-free ds_read_b128 (2/bankgroup).
// ---------------------------------------------------------------------------
__global__ __launch_bounds__(256) void k_deltatau_mfma(
        const unsigned short* __restrict__ x_hi,
        const unsigned short* __restrict__ x_lo,
        const unsigned short* __restrict__ Weff_hi,
        const unsigned short* __restrict__ Weff_lo,
        const float* __restrict__ bias_eff,
        float* __restrict__ delta)
{
    const int m0  = blockIdx.x * 128;
    const int e0  = blockIdx.y * 64;
    const int s   = blockIdx.z;
    const int tid  = threadIdx.x;
    const int wid  = tid >> 6;
    const int lane = tid & 63;
    const int l15  = lane & 15;
    const int quad = lane >> 4;
    const int r_in = lane >> 2;   // staging: row within 16-row chunk
    const int c_in = lane & 3;    // staging: physical 16B chunk within 64B row

    __shared__ unsigned short Ah[128 * 32];
    __shared__ unsigned short Al[128 * 32];
    __shared__ unsigned short Bh[128 * 32];
    __shared__ unsigned short Bl[128 * 32];

    f32x4 acc[2][8];
    #pragma unroll
    for (int i = 0; i < 2; ++i)
        #pragma unroll
        for (int j = 0; j < 8; ++j)
            acc[i][j] = (f32x4){0.f, 0.f, 0.f, 0.f};

    for (int k0 = 0; k0 < F_; k0 += 32) {   // 2 iterations
        #pragma unroll
        for (int call = 0; call < 2; ++call) {
            const int base = wid * 32 + call * 16;
            const int r    = base + r_in;
            const int cl   = (c_in - (r >> 1)) & 3;     // logical chunk for this lane
            const size_t ga = (size_t)(m0 + r) * F_ + k0 + cl * 8;
            async_copy16(x_hi + ga, &Ah[base * 32]);
            async_copy16(x_lo + ga, &Al[base * 32]);
            const int gn = (r < 64) ? (e0 + r) : (256 + e0 + (r - 64));
            const size_t gb = ((size_t)s * 512 + gn) * F_ + k0 + cl * 8;
            async_copy16(Weff_hi + gb, &Bh[base * 32]);
            async_copy16(Weff_lo + gb, &Bl[base * 32]);
        }
        __syncthreads();

        bf16x8 bhf[8], blf[8];
        #pragma unroll
        for (int nj = 0; nj < 8; ++nj) {
            const int row = nj * 16 + l15;
            const int pc  = (quad + (row >> 1)) & 3;
            const int off = row * 32 + pc * 8;
            bhf[nj] = *(const bf16x8*)&Bh[off];
            blf[nj] = *(const bf16x8*)&Bl[off];
        }
        #pragma unroll
        for (int mi = 0; mi < 2; ++mi) {
            const int row = wid * 32 + mi * 16 + l15;
            const int pc  = (quad + (row >> 1)) & 3;
            const int aoff = row * 32 + pc * 8;
            bf16x8 ah = *(const bf16x8*)&Ah[aoff];
            bf16x8 al = *(const bf16x8*)&Al[aoff];
            #pragma unroll
            for (int nj = 0; nj < 8; ++nj) {
                acc[mi][nj] = __builtin_amdgcn_mfma_f32_16x16x32_bf16(ah, bhf[nj], acc[mi][nj], 0, 0, 0);
                acc[mi][nj] = __builtin_amdgcn_mfma_f32_16x16x32_bf16(ah, blf[nj], acc[mi][nj], 0, 0, 0);
                acc[mi][nj] = __builtin_amdgcn_mfma_f32_16x16x32_bf16(al, bhf[nj], acc[mi][nj], 0, 0, 0);
            }
        }
        __syncthreads();
    }

    // epilogue: pair delta-acc (nj=j) with tau-acc (nj=j+4), fuse activations
    float* dout = delta + (size_t)s * BL_ * D_;
    const float* bias = bias_eff + s * 512;
    #pragma unroll
    for (int mi = 0; mi < 2; ++mi) {
        #pragma unroll
        for (int j = 0; j < 4; ++j) {
            const int e = e0 + j * 16 + l15;
            const float bde = bias[e];
            const float bte = bias[256 + e];
            #pragma unroll
            for (int r = 0; r < 4; ++r) {
                const int m = m0 + wid * 32 + mi * 16 + quad * 4 + r;
                const float pd = acc[mi][j][r] + bde;
                const float sp = fmaxf(pd, 0.f) + __logf(1.f + __expf(-fabsf(pd)));
                const float sg = 1.f / (1.f + __expf(-(acc[mi][j + 4][r] + bte)));
                dout[(size_t)m * D_ + e] = sp * sg;
            }
        }
    }
}

// ---------------------------------------------------------------------------
// Kernel 3: Bm = x @ WBeff + bbias   per s  (M=16384, K=64, N=16)
// ---------------------------------------------------------------------------
__global__ __launch_bounds__(256) void k_bm(const float* __restrict__ x,
                                            const float* __restrict__ WBeff,
                                            const float* __restrict__ bbias,
                                            float* __restrict__ Bm)
{
    const int s   = blockIdx.y;
    const int tid = threadIdx.x;
    const int row = blockIdx.x * 16 + (tid >> 4);
    const int n   = tid & 15;
    const float* we = WBeff + (size_t)s * F_ * N_;
    const float* xr = x + (size_t)row * F_;
    float acc = bbias[s * N_ + n];
    #pragma unroll 4
    for (int k = 0; k < F_; k += 4) {
        float4 xv = *(const float4*)(xr + k);
        acc += xv.x * we[(k+0)*N_ + n];
        acc += xv.y * we[(k+1)*N_ + n];
        acc += xv.z * we[(k+2)*N_ + n];
        acc += xv.w * we[(k+3)*N_ + n];
    }
    Bm[((size_t)s * BL_ + row) * N_ + n] = acc;
}

// ---------------------------------------------------------------------------
// Kernel 4a: parallel scan, stage 1. A constant per (s,d,n) chain, so decay
// over a span is exp(A * sum(delta)). Each block: one (s,b,16-d,chunk).
// ---------------------------------------------------------------------------
__global__ __launch_bounds__(256) void k_scan_part(const float* __restrict__ delta,
                                                   const float* __restrict__ h,
                                                   const float* __restrict__ Bm,
                                                   const float* __restrict__ A_log,
                                                   float* __restrict__ part,
                                                   float* __restrict__ csum)
{
    const int dtile = blockIdx.x >> 2;          // 0..15
    const int c     = blockIdx.x & 3;           // chunk 0..3
    const int b     = blockIdx.y;
    const int s     = blockIdx.z;
    const int d0    = dtile * 16;
    const int tc0   = c * TC_;
    const int tid   = threadIdx.x;
    const int dl    = tid & 15;
    const int nl    = tid >> 4;
    const int d     = d0 + dl;

    const float A = -__expf(A_log[((size_t)s * D_ + d) * N_ + nl]);

    const float* dptr = delta + ((size_t)s * BL_ + (size_t)b * L_) * D_ + d0;
    const float* hptr = h + ((size_t)b * L_) * D_ + d0;
    const float* bptr = Bm + ((size_t)s * BL_ + (size_t)b * L_) * N_;

    __shared__ float sd[32][16];
    __shared__ float sh[32][16];
    __shared__ float sb[32][16];

    float state = 0.f;
    float accs  = 0.f;   // running suffix sum of delta (exclusive), per-d

    for (int sc = (TC_/32) - 1; sc >= 0; --sc) {
        for (int i = tid; i < 384; i += 256) {
            int grp = i >> 7;        // 0: delta, 1: h, 2: Bm
            int idx = i & 127;
            int tt  = idx >> 2;
            int q   = idx & 3;
            int tg  = tc0 + sc * 32 + tt;
            if (grp == 0)
                *(float4*)&sd[tt][q*4] = *(const float4*)(dptr + (size_t)tg * D_ + q*4);
            else if (grp == 1)
                *(float4*)&sh[tt][q*4] = *(const float4*)(hptr + (size_t)tg * D_ + q*4);
            else
                *(float4*)&sb[tt][q*4] = *(const float4*)(bptr + (size_t)tg * N_ + q*4);
        }
        __syncthreads();
        #pragma unroll
        for (int tt = 31; tt >= 0; --tt) {
            float dlt = sd[tt][dl];
            float e   = __expf(A * accs);
            state += dlt * sh[tt][dl] * sb[tt][nl] * e;
            accs  += dlt;
        }
        __syncthreads();
    }

    part[((((size_t)s * B_ + b) * NCH_ + c) * D_ + d) * N_ + nl] = state;
    if (nl == 0)
        csum[(((size_t)s * B_ + b) * NCH_ + c) * D_ + d] = accs;
}

// ---------------------------------------------------------------------------
// Kernel 4b: combine chunks: state = sum_c exp(A * tail_c) * part_c
// ---------------------------------------------------------------------------
__global__ __launch_bounds__(256) void k_scan_comb(const float* __restrict__ part,
                                                   const float* __restrict__ csum,
                                                   const float* __restrict__ A_log,
                                                   float* __restrict__ states)
{
    const int b   = blockIdx.y;
    const int s   = blockIdx.z;
    const int tid = threadIdx.x;
    const int dl  = tid & 15;
    const int nl  = tid >> 4;
    const int d   = blockIdx.x * 16 + dl;

    const float A = -__expf(A_log[((size_t)s * D_ + d) * N_ + nl]);

    const size_t cbase = ((size_t)s * B_ + b) * NCH_;
    float cs[NCH_];
    #pragma unroll
    for (int c = 0; c < NCH_; ++c) cs[c] = csum[(cbase + c) * D_ + d];

    float state = 0.f;
    float tail = 0.f;
    #pragma unroll
    for (int c = NCH_ - 1; c >= 0; --c) {
        float p = part[((cbase + c) * D_ + d) * N_ + nl];
        state += __expf(A * tail) * p;
        tail  += cs[c];
    }
    states[(((size_t)s * B_ + b) * D_ + d) * N_ + nl] = state;
}

// ---------------------------------------------------------------------------
// Kernel 5: final readout. One block per batch element b.
// ---------------------------------------------------------------------------
__global__ __launch_bounds__(256) void k_final(const float* __restrict__ h,
                                               const float* __restrict__ states,
                                               const float* __restrict__ WC,
                                               const float* __restrict__ Dp,
                                               const float* __restrict__ Wout,
                                               const float* __restrict__ ln_g,
                                               const float* __restrict__ ln_b,
                                               const float* __restrict__ W1,
                                               const float* __restrict__ b1,
                                               const float* __restrict__ W2,
                                               const float* __restrict__ b2,
                                               float* __restrict__ out)
{
    const int b   = blockIdx.x;
    const int tid = threadIdx.x;

    __shared__ float hl[D_];
    __shared__ float cm[S_][N_];
    __shared__ float ys[S_][D_];
    __shared__ float zv[D_];
    __shared__ float red1[256];
    __shared__ float red2[256];
    __shared__ float r1[H_];

    hl[tid] = h[((size_t)b * L_ + (L_ - 1)) * D_ + tid];
    __syncthreads();

    if (tid < S_ * N_) {
        int s = tid >> 4, n = tid & 15;
        float a = 0.f;
        for (int d = 0; d < D_; ++d) a += hl[d] * WC[((size_t)s * D_ + d) * N_ + n];
        cm[s][n] = a;
    }
    __syncthreads();

    for (int s = 0; s < S_; ++s) {
        const float* st = states + (((size_t)s * B_ + b) * D_ + tid) * N_;
        float a = 0.f;
        #pragma unroll
        for (int n = 0; n < N_; ++n) a += st[n] * cm[s][n];
        ys[s][tid] = a + hl[tid] * Dp[s * D_ + tid];
    }
    __syncthreads();

    float v;
    {
        float a = 0.f;
        for (int s = 0; s < S_; ++s) {
            const float* wo = Wout + (size_t)s * D_ * D_;
            for (int d = 0; d < D_; ++d) a += ys[s][d] * wo[(size_t)d * D_ + tid];
        }
        v = a * (1.f / S_);
    }

    red1[tid] = v;
    red2[tid] = v * v;
    __syncthreads();
    for (int off = 128; off > 0; off >>= 1) {
        if (tid < off) { red1[tid] += red1[tid + off]; red2[tid] += red2[tid + off]; }
        __syncthreads();
    }
    const float mu  = red1[0] * (1.f / D_);
    const float var = red2[0] * (1.f / D_) - mu * mu;
    const float z = (v - mu) * rsqrtf(var + EPS_) * ln_g[tid] + ln_b[tid];
    zv[tid] = z;
    __syncthreads();

    if (tid < H_) {
        float a = b1[tid];
        for (int e = 0; e < D_; ++e) a += zv[e] * W1[(size_t)e * H_ + tid];
        r1[tid] = fmaxf(a, 0.f);
    }
    __syncthreads();
    if (tid == 0) {
        float a = b2[0];
        for (int j = 0; j < H_; ++j) a += r1[j] * W2[j];
        out[b] = a;
    }
}

// ---------------------------------------------------------------------------
extern "C" void kernel_launch(void* const* d_in, const int* in_sizes, int n_in,
                              void* d_out, int out_size, void* d_ws, size_t ws_size,
                              hipStream_t stream)
{
    const float* x     = (const float*)d_in[0];
    const float* Win   = (const float*)d_in[1];
    const float* bin   = (const float*)d_in[2];
    const float* Wd    = (const float*)d_in[3];
    const float* bd    = (const float*)d_in[4];
    const float* WB    = (const float*)d_in[5];
    const float* WC    = (const float*)d_in[6];
    const float* Wtau  = (const float*)d_in[7];
    const float* A_log = (const float*)d_in[8];
    const float* Dp    = (const float*)d_in[9];
    const float* Wout  = (const float*)d_in[10];
    const float* ln_g  = (const float*)d_in[11];
    const float* ln_b  = (const float*)d_in[12];
    const float* W1    = (const float*)d_in[13];
    const float* b1    = (const float*)d_in[14];
    const float* W2    = (const float*)d_in[15];
    const float* b2    = (const float*)d_in[16];
    float* out = (float*)d_out;

    char* ws = (char*)d_ws;
    const size_t MB = 1024 * 1024;
    float*          h        = (float*)(ws);                       // 16 MiB
    float*          delta    = (float*)(ws + 16 * MB);             // 32 MiB
    float*          Bm       = (float*)(ws + 48 * MB);             //  2 MiB
    float*          states   = (float*)(ws + 50 * MB);             //  0.5 MiB
    float*          part     = (float*)(ws + 51 * MB);             //  2 MiB
    float*          csum     = (float*)(ws + 53 * MB);             //  0.5 MiB
    unsigned short* x_hi     = (unsigned short*)(ws + 54 * MB);    //  2 MiB
    unsigned short* x_lo     = (unsigned short*)(ws + 56 * MB);    //  2 MiB
    unsigned short* Weff_hi  = (unsigned short*)(ws + 58 * MB);    //  128 KiB
    unsigned short* Weff_lo  = (unsigned short*)(ws + 58 * MB + 128 * 1024);
    float*          bias_eff = (float*)(ws + 58 * MB + 256 * 1024);//  4 KiB
    float*          WBeff    = (float*)(ws + 58 * MB + 260 * 1024);//  8 KiB
    float*          bbias    = (float*)(ws + 58 * MB + 268 * 1024);//  128 B

    dim3 blk2d(16, 16);
    hipLaunchKernelGGL(k_xsplit,        dim3(BL_*F_/1024),          dim3(256), 0, stream, x, x_hi, x_lo);
    hipLaunchKernelGGL(k_weff,          dim3(512, S_),              dim3(64),  0, stream, Win, bin, Wd, bd, Wtau, Weff_hi, Weff_lo, bias_eff);
    hipLaunchKernelGGL(k_deltatau_mfma, dim3(BL_/128, 4, S_),       dim3(256), 0, stream, x_hi, x_lo, Weff_hi, Weff_lo, bias_eff, delta);
    hipLaunchKernelGGL(k_wbeff,         dim3(4, S_),                dim3(256), 0, stream, Win, bin, WB, WBeff, bbias);
    hipLaunchKernelGGL(k_bm,            dim3(BL_/16, S_),           dim3(256), 0, stream, x, WBeff, bbias, Bm);
    hipLaunchKernelGGL(k_inproj,        dim3(BL_/64, D_/64),        blk2d,     0, stream, x, Win, bin, h);
    hipLaunchKernelGGL(k_scan_part,     dim3((D_/16)*NCH_, B_, S_), dim3(256), 0, stream, delta, h, Bm, A_log, part, csum);
    hipLaunchKernelGGL(k_scan_comb,     dim3(D_/16, B_, S_),        dim3(256), 0, stream, part, csum, A_log, states);
    hipLaunchKernelGGL(k_final,         dim3(B_),                   dim3(256), 0, stream,
                       h, states, WC, Dp, Wout, ln_g, ln_b, W1, b1, W2, b2, out);
}

// Round 5
// 187.751 us; speedup vs baseline: 1.9103x; 1.1578x over previous
//
#include <hip/hip_runtime.h>
#include <hip/hip_bf16.h>
#include <math.h>

#define B_   16
#define L_   1024
#define F_   64
#define D_   256
#define S_   2
#define N_   16
#define H_   32
#define EPS_ 1e-5f
#define BL_  (B_*L_)
#define NCH_ 4          // t-chunks for the parallel scan
#define TC_  (L_/NCH_)  // 256 timesteps per chunk
#define SUB_ 64         // timesteps per staged sub-chunk

typedef __attribute__((ext_vector_type(8))) short  bf16x8;
typedef __attribute__((ext_vector_type(4))) float  f32x4;

typedef const __attribute__((address_space(1))) void* gas_ptr;
typedef __attribute__((address_space(3))) void*       las_ptr;

__device__ inline void async_copy16(const void* g, void* l) {
    __builtin_amdgcn_global_load_lds((gas_ptr)g, (las_ptr)l, 16, 0, 0);
}

__device__ inline unsigned short f2bf_rne(float x) {
    union { float f; unsigned u; } v; v.f = x;
    unsigned r = v.u + 0x7fff + ((v.u >> 16) & 1);
    return (unsigned short)(r >> 16);
}
__device__ inline float bf2f(unsigned short h) {
    union { float f; unsigned u; } v; v.u = ((unsigned)h) << 16;
    return v.f;
}

// ---------------------------------------------------------------------------
// Kernel 0: split x into bf16 hi/lo  (BL*F = 1M elements)
// ---------------------------------------------------------------------------
__global__ __launch_bounds__(256) void k_xsplit(const float* __restrict__ x,
                                                unsigned short* __restrict__ xh,
                                                unsigned short* __restrict__ xl)
{
    const int i = (blockIdx.x * 256 + threadIdx.x) * 4;
    float4 v = *(const float4*)(x + i);
    ushort4 h4, l4;
    unsigned short hh;
    hh = f2bf_rne(v.x); h4.x = hh; l4.x = f2bf_rne(v.x - bf2f(hh));
    hh = f2bf_rne(v.y); h4.y = hh; l4.y = f2bf_rne(v.y - bf2f(hh));
    hh = f2bf_rne(v.z); h4.z = hh; l4.z = f2bf_rne(v.z - bf2f(hh));
    hh = f2bf_rne(v.w); h4.w = hh; l4.w = f2bf_rne(v.w - bf2f(hh));
    *(ushort4*)(xh + i) = h4;
    *(ushort4*)(xl + i) = l4;
}

// ---------------------------------------------------------------------------
// Kernel 1: all weight prep in one launch. 64 threads/block.
//  blocks [0, S*512):        Weff[s][n][f] = Win @ W{d,tau} col  (+ biases)
//  blocks [S*512, +D):       WinT[d][f] = Win[f][d]               (split)
//  blocks [S*512+D, +S*N):   WBe[s][n][f] = Win @ WB col          (+ bbias)
// ---------------------------------------------------------------------------
__global__ __launch_bounds__(64) void k_prep_w(const float* __restrict__ Win,
                                               const float* __restrict__ bin,
                                               const float* __restrict__ Wd,
                                               const float* __restrict__ bd,
                                               const float* __restrict__ Wt,
                                               const float* __restrict__ WB,
                                               unsigned short* __restrict__ Weff_hi,
                                               unsigned short* __restrict__ Weff_lo,
                                               float* __restrict__ bias_eff,
                                               unsigned short* __restrict__ WinT_hi,
                                               unsigned short* __restrict__ WinT_lo,
                                               unsigned short* __restrict__ WBe_hi,
                                               unsigned short* __restrict__ WBe_lo,
                                               float* __restrict__ bbias)
{
    const int i = blockIdx.x;
    const int f = threadIdx.x;
    __shared__ float col[D_];

    if (i < S_ * 512) {
        const int s = i >> 9, n = i & 511;
        const float* W = (n < 256) ? (Wd + (size_t)s * D_ * D_) : (Wt + (size_t)s * D_ * D_);
        const int e = n & 255;
        for (int d = f; d < D_; d += 64) col[d] = W[(size_t)d * D_ + e];
        __syncthreads();
        float a = 0.f;
        for (int d = 0; d < D_; ++d) a += Win[(size_t)f * D_ + d] * col[d];
        unsigned short hi = f2bf_rne(a);
        size_t o = ((size_t)s * 512 + n) * F_ + f;
        Weff_hi[o] = hi;
        Weff_lo[o] = f2bf_rne(a - bf2f(hi));
        if (f == 0) {
            float bb = 0.f;
            for (int d = 0; d < D_; ++d) bb += bin[d] * col[d];
            if (n < 256) bb += bd[s * D_ + e];
            bias_eff[s * 512 + n] = bb;
        }
    } else if (i < S_ * 512 + D_) {
        const int d = i - S_ * 512;
        float v = Win[(size_t)f * D_ + d];
        unsigned short hi = f2bf_rne(v);
        size_t o = (size_t)d * F_ + f;
        WinT_hi[o] = hi;
        WinT_lo[o] = f2bf_rne(v - bf2f(hi));
    } else {
        const int idx = i - (S_ * 512 + D_);
        const int s = idx >> 4, n = idx & 15;
        const float* wb = WB + (size_t)s * D_ * N_;
        float a = 0.f;
        for (int d = 0; d < D_; ++d) a += Win[(size_t)f * D_ + d] * wb[(size_t)d * N_ + n];
        unsigned short hi = f2bf_rne(a);
        size_t o = ((size_t)s * N_ + n) * F_ + f;
        WBe_hi[o] = hi;
        WBe_lo[o] = f2bf_rne(a - bf2f(hi));
        if (f == 0) {
            float bb = 0.f;
            for (int d = 0; d < D_; ++d) bb += bin[d] * wb[(size_t)d * N_ + n];
            bbias[s * N_ + n] = bb;
        }
    }
}

// ---------------------------------------------------------------------------
// Kernel 2: FUSED gemm + activation + scan. One block per (s, b, d-tile,
// t-chunk). Per 64-t sub-chunk: MFMA computes delta/tau/h/Bm tiles from the
// LDS-staged x slice and 64-col weight strip (cols: 16 delta, 16 tau,
// 16 Win, 16 WB), epilogue fuses softplus*sigmoid and q=delta*h into padded
// LDS tiles, then 256 (d,n)-lanes run the backward suffix scan.
// LDS tiles chunk-swizzled: phys 16B chunk = (logical + row) & 7.
// ---------------------------------------------------------------------------
__global__ __launch_bounds__(256) void k_fused_scan(
        const unsigned short* __restrict__ x_hi,
        const unsigned short* __restrict__ x_lo,
        const unsigned short* __restrict__ Weff_hi,
        const unsigned short* __restrict__ Weff_lo,
        const unsigned short* __restrict__ WinT_hi,
        const unsigned short* __restrict__ WinT_lo,
        const unsigned short* __restrict__ WBe_hi,
        const unsigned short* __restrict__ WBe_lo,
        const float* __restrict__ bias_eff,
        const float* __restrict__ bin,
        const float* __restrict__ bbias,
        const float* __restrict__ A_log,
        float* __restrict__ part,
        float* __restrict__ csum)
{
    const int dtile = blockIdx.x >> 2;
    const int c     = blockIdx.x & 3;
    const int b     = blockIdx.y;
    const int s     = blockIdx.z;
    const int d0    = dtile * 16;
    const int tid   = threadIdx.x;
    const int wid   = tid >> 6;
    const int lane  = tid & 63;
    const int l15   = lane & 15;
    const int quad  = lane >> 4;
    const int dl    = tid & 15;   // scan-phase: d within tile
    const int nl    = tid >> 4;   // scan-phase: n

    __shared__ unsigned short Xh[SUB_ * F_];   // [t][f] bf16 hi, rows 128B
    __shared__ unsigned short Xl[SUB_ * F_];
    __shared__ unsigned short Wh[64 * F_];     // [col][f]: 0-15 d,16-31 tau,32-47 Win,48-63 WB
    __shared__ unsigned short Wl[64 * F_];
    __shared__ float sdl[SUB_][17];            // delta
    __shared__ float sq [SUB_][17];            // delta*h
    __shared__ float sb [SUB_][17];            // Bm

    const int r8 = lane >> 3;   // staging: row within 8-row call
    const int c8 = lane & 7;    // staging: physical 16B chunk within 128B row

    // ---- stage W strip once (wave wid = col group wid)
    #pragma unroll
    for (int call = 0; call < 2; ++call) {
        const int rr = call * 8 + r8;           // row within group (0..15)
        const int ar = wid * 16 + rr;           // absolute W row (0..63)
        const int lc = (c8 - ar) & 7;           // logical chunk for this lane
        const unsigned short *gh, *gl;
        if (wid == 0)      { size_t o = ((size_t)s * 512 + d0 + rr) * F_ + lc * 8;       gh = Weff_hi + o; gl = Weff_lo + o; }
        else if (wid == 1) { size_t o = ((size_t)s * 512 + 256 + d0 + rr) * F_ + lc * 8; gh = Weff_hi + o; gl = Weff_lo + o; }
        else if (wid == 2) { size_t o = ((size_t)(d0 + rr)) * F_ + lc * 8;               gh = WinT_hi + o; gl = WinT_lo + o; }
        else               { size_t o = ((size_t)s * N_ + rr) * F_ + lc * 8;             gh = WBe_hi + o;  gl = WBe_lo + o; }
        async_copy16(gh, &Wh[(wid * 16 + call * 8) * F_]);
        async_copy16(gl, &Wl[(wid * 16 + call * 8) * F_]);
    }

    // per-lane constants
    const float bias_d = bias_eff[s * 512 + d0 + l15];
    const float bias_t = bias_eff[s * 512 + 256 + d0 + l15];
    const float bin_v  = bin[d0 + l15];
    const float bb_v   = bbias[s * N_ + l15];
    const float A = -__expf(A_log[((size_t)s * D_ + d0 + dl) * N_ + nl]);

    float state = 0.f;
    float accs  = 0.f;

    for (int sc = (TC_ / SUB_) - 1; sc >= 0; --sc) {
        // ---- stage x sub-chunk (wave wid: t-rows wid*16..+16)
        #pragma unroll
        for (int call = 0; call < 2; ++call) {
            const int ar = wid * 16 + call * 8 + r8;         // t within sub-chunk
            const int lc = (c8 - ar) & 7;
            const int tg = c * TC_ + sc * SUB_ + ar;
            const size_t o = ((size_t)b * L_ + tg) * F_ + lc * 8;
            async_copy16(x_hi + o, &Xh[(wid * 16 + call * 8) * F_]);
            async_copy16(x_lo + o, &Xl[(wid * 16 + call * 8) * F_]);
        }
        __syncthreads();   // W+X staged; also protects sdl/sq/sb vs prev scan

        // ---- MFMA: this wave's 16 t-rows x 4 col groups, K=64
        f32x4 acc[4];
        #pragma unroll
        for (int g = 0; g < 4; ++g) acc[g] = (f32x4){0.f, 0.f, 0.f, 0.f};
        #pragma unroll
        for (int ks = 0; ks < 2; ++ks) {
            const int arow = wid * 16 + l15;
            const int pcA  = ((ks * 4 + quad) + arow) & 7;
            bf16x8 ah = *(const bf16x8*)&Xh[arow * F_ + pcA * 8];
            bf16x8 al = *(const bf16x8*)&Xl[arow * F_ + pcA * 8];
            #pragma unroll
            for (int g = 0; g < 4; ++g) {
                const int brow = g * 16 + l15;
                const int pcB  = ((ks * 4 + quad) + brow) & 7;
                bf16x8 bh = *(const bf16x8*)&Wh[brow * F_ + pcB * 8];
                bf16x8 bl = *(const bf16x8*)&Wl[brow * F_ + pcB * 8];
                acc[g] = __builtin_amdgcn_mfma_f32_16x16x32_bf16(ah, bh, acc[g], 0, 0, 0);
                acc[g] = __builtin_amdgcn_mfma_f32_16x16x32_bf16(ah, bl, acc[g], 0, 0, 0);
                acc[g] = __builtin_amdgcn_mfma_f32_16x16x32_bf16(al, bh, acc[g], 0, 0, 0);
            }
        }

        // ---- epilogue: C layout col=l15, row=quad*4+r  ->  LDS scan tiles
        #pragma unroll
        for (int r = 0; r < 4; ++r) {
            const int tr = wid * 16 + quad * 4 + r;
            const float pd  = acc[0][r] + bias_d;
            const float sp  = fmaxf(pd, 0.f) + __logf(1.f + __expf(-fabsf(pd)));
            const float sg  = 1.f / (1.f + __expf(-(acc[1][r] + bias_t)));
            const float dlt = sp * sg;
            const float hv  = acc[2][r] + bin_v;
            sdl[tr][l15] = dlt;
            sq [tr][l15] = dlt * hv;
            sb [tr][l15] = acc[3][r] + bb_v;
        }
        __syncthreads();

        // ---- backward suffix scan over this sub-chunk
        #pragma unroll 8
        for (int tt = SUB_ - 1; tt >= 0; --tt) {
            const float dlt = sdl[tt][dl];
            const float e   = __expf(A * accs);
            state = fmaf(sq[tt][dl] * sb[tt][nl], e, state);
            accs += dlt;
        }
    }

    const size_t pb = ((size_t)s * B_ + b) * NCH_ + c;
    part[(pb * D_ + d0 + dl) * N_ + nl] = state;
    if (nl == 0)
        csum[pb * D_ + d0 + dl] = accs;
}

// ---------------------------------------------------------------------------
// Kernel 3: combine chunks: state = sum_c exp(A * tail_c) * part_c
// ---------------------------------------------------------------------------
__global__ __launch_bounds__(256) void k_scan_comb(const float* __restrict__ part,
                                                   const float* __restrict__ csum,
                                                   const float* __restrict__ A_log,
                                                   float* __restrict__ states)
{
    const int b   = blockIdx.y;
    const int s   = blockIdx.z;
    const int tid = threadIdx.x;
    const int dl  = tid & 15;
    const int nl  = tid >> 4;
    const int d   = blockIdx.x * 16 + dl;

    const float A = -__expf(A_log[((size_t)s * D_ + d) * N_ + nl]);

    const size_t cbase = ((size_t)s * B_ + b) * NCH_;
    float cs[NCH_];
    #pragma unroll
    for (int c = 0; c < NCH_; ++c) cs[c] = csum[(cbase + c) * D_ + d];

    float state = 0.f;
    float tail = 0.f;
    #pragma unroll
    for (int c = NCH_ - 1; c >= 0; --c) {
        float p = part[((cbase + c) * D_ + d) * N_ + nl];
        state += __expf(A * tail) * p;
        tail  += cs[c];
    }
    states[(((size_t)s * B_ + b) * D_ + d) * N_ + nl] = state;
}

// ---------------------------------------------------------------------------
// Kernel 4: final readout. One block per batch element b. h_last recomputed
// from x directly (h array no longer materialized).
// ---------------------------------------------------------------------------
__global__ __launch_bounds__(256) void k_final(const float* __restrict__ x,
                                               const float* __restrict__ Win,
                                               const float* __restrict__ bin,
                                               const float* __restrict__ states,
                                               const float* __restrict__ WC,
                                               const float* __restrict__ Dp,
                                               const float* __restrict__ Wout,
                                               const float* __restrict__ ln_g,
                                               const float* __restrict__ ln_b,
                                               const float* __restrict__ W1,
                                               const float* __restrict__ b1,
                                               const float* __restrict__ W2,
                                               const float* __restrict__ b2,
                                               float* __restrict__ out)
{
    const int b   = blockIdx.x;
    const int tid = threadIdx.x;

    __shared__ float xr[F_];
    __shared__ float hl[D_];
    __shared__ float cm[S_][N_];
    __shared__ float ys[S_][D_];
    __shared__ float zv[D_];
    __shared__ float red1[256];
    __shared__ float red2[256];
    __shared__ float r1[H_];

    if (tid < F_) xr[tid] = x[((size_t)b * L_ + (L_ - 1)) * F_ + tid];
    __syncthreads();

    {   // h_last[d] = x_last . Win[:,d] + bin[d]
        float a = bin[tid];
        for (int f = 0; f < F_; ++f) a += xr[f] * Win[(size_t)f * D_ + tid];
        hl[tid] = a;
    }
    __syncthreads();

    if (tid < S_ * N_) {
        int s = tid >> 4, n = tid & 15;
        float a = 0.f;
        for (int d = 0; d < D_; ++d) a += hl[d] * WC[((size_t)s * D_ + d) * N_ + n];
        cm[s][n] = a;
    }
    __syncthreads();

    for (int s = 0; s < S_; ++s) {
        const float* st = states + (((size_t)s * B_ + b) * D_ + tid) * N_;
        float a = 0.f;
        #pragma unroll
        for (int n = 0; n < N_; ++n) a += st[n] * cm[s][n];
        ys[s][tid] = a + hl[tid] * Dp[s * D_ + tid];
    }
    __syncthreads();

    float v;
    {
        float a = 0.f;
        for (int s = 0; s < S_; ++s) {
            const float* wo = Wout + (size_t)s * D_ * D_;
            for (int d = 0; d < D_; ++d) a += ys[s][d] * wo[(size_t)d * D_ + tid];
        }
        v = a * (1.f / S_);
    }

    red1[tid] = v;
    red2[tid] = v * v;
    __syncthreads();
    for (int off = 128; off > 0; off >>= 1) {
        if (tid < off) { red1[tid] += red1[tid + off]; red2[tid] += red2[tid + off]; }
        __syncthreads();
    }
    const float mu  = red1[0] * (1.f / D_);
    const float var = red2[0] * (1.f / D_) - mu * mu;
    const float z = (v - mu) * rsqrtf(var + EPS_) * ln_g[tid] + ln_b[tid];
    zv[tid] = z;
    __syncthreads();

    if (tid < H_) {
        float a = b1[tid];
        for (int e = 0; e < D_; ++e) a += zv[e] * W1[(size_t)e * H_ + tid];
        r1[tid] = fmaxf(a, 0.f);
    }
    __syncthreads();
    if (tid == 0) {
        float a = b2[0];
        for (int j = 0; j < H_; ++j) a += r1[j] * W2[j];
        out[b] = a;
    }
}

// ---------------------------------------------------------------------------
extern "C" void kernel_launch(void* const* d_in, const int* in_sizes, int n_in,
                              void* d_out, int out_size, void* d_ws, size_t ws_size,
                              hipStream_t stream)
{
    const float* x     = (const float*)d_in[0];
    const float* Win   = (const float*)d_in[1];
    const float* bin   = (const float*)d_in[2];
    const float* Wd    = (const float*)d_in[3];
    const float* bd    = (const float*)d_in[4];
    const float* WB    = (const float*)d_in[5];
    const float* WC    = (const float*)d_in[6];
    const float* Wtau  = (const float*)d_in[7];
    const float* A_log = (const float*)d_in[8];
    const float* Dp    = (const float*)d_in[9];
    const float* Wout  = (const float*)d_in[10];
    const float* ln_g  = (const float*)d_in[11];
    const float* ln_b  = (const float*)d_in[12];
    const float* W1    = (const float*)d_in[13];
    const float* b1    = (const float*)d_in[14];
    const float* W2    = (const float*)d_in[15];
    const float* b2    = (const float*)d_in[16];
    float* out = (float*)d_out;

    char* ws = (char*)d_ws;
    const size_t MB = 1024 * 1024;
    const size_t KB = 1024;
    unsigned short* x_hi     = (unsigned short*)(ws);                      // 2 MiB
    unsigned short* x_lo     = (unsigned short*)(ws + 2 * MB);             // 2 MiB
    unsigned short* Weff_hi  = (unsigned short*)(ws + 4 * MB);             // 128 KiB
    unsigned short* Weff_lo  = (unsigned short*)(ws + 4 * MB + 128 * KB);  // 128 KiB
    unsigned short* WinT_hi  = (unsigned short*)(ws + 4 * MB + 256 * KB);  // 32 KiB
    unsigned short* WinT_lo  = (unsigned short*)(ws + 4 * MB + 288 * KB);  // 32 KiB
    unsigned short* WBe_hi   = (unsigned short*)(ws + 4 * MB + 320 * KB);  // 4 KiB
    unsigned short* WBe_lo   = (unsigned short*)(ws + 4 * MB + 324 * KB);  // 4 KiB
    float*          bias_eff = (float*)(ws + 4 * MB + 328 * KB);           // 4 KiB
    float*          bbias    = (float*)(ws + 4 * MB + 332 * KB);           // 128 B
    float*          part     = (float*)(ws + 5 * MB);                      // 2 MiB
    float*          csum     = (float*)(ws + 7 * MB);                      // 128 KiB
    float*          states   = (float*)(ws + 8 * MB);                      // 0.5 MiB

    hipLaunchKernelGGL(k_xsplit,    dim3(BL_ * F_ / 1024),        dim3(256), 0, stream, x, x_hi, x_lo);
    hipLaunchKernelGGL(k_prep_w,    dim3(S_ * 512 + D_ + S_ * N_),dim3(64),  0, stream,
                       Win, bin, Wd, bd, Wtau, WB,
                       Weff_hi, Weff_lo, bias_eff, WinT_hi, WinT_lo, WBe_hi, WBe_lo, bbias);
    hipLaunchKernelGGL(k_fused_scan, dim3((D_ / 16) * NCH_, B_, S_), dim3(256), 0, stream,
                       x_hi, x_lo, Weff_hi, Weff_lo, WinT_hi, WinT_lo, WBe_hi, WBe_lo,
                       bias_eff, bin, bbias, A_log, part, csum);
    hipLaunchKernelGGL(k_scan_comb, dim3(D_ / 16, B_, S_),        dim3(256), 0, stream, part, csum, A_log, states);
    hipLaunchKernelGGL(k_final,     dim3(B_),                     dim3(256), 0, stream,
                       x, Win, bin, states, WC, Dp, Wout, ln_g, ln_b, W1, b1, W2, b2, out);
}